// Round 8
// baseline (2508.502 us; speedup 1.0000x reference)
//
#include <hip/hip_runtime.h>
#include <math.h>
#include <stdint.h>

// Problem constants
#define TT 4
#define BB 16
#define CC 256
#define NN 1024
#define NT 16        // spatial positions per block
#define EPSF 1e-5f
#define EPS_R 3e-3f  // rescue margin; GEMM abs error bound ~5e-6 << this

typedef __attribute__((ext_vector_type(8))) short short8;  // 8 bf16 (4 VGPR)
typedef __attribute__((ext_vector_type(4))) float f32x4;
#define MFMA __builtin_amdgcn_mfma_f32_16x16x32_bf16

// bf16 split helpers (pure bit ops, RNE). x = hi + mid + lo covers 24 bits.
__device__ __forceinline__ uint32_t f2bf(float x) {
  const uint32_t u = __float_as_uint(x);
  return (u + 0x7FFFu + ((u >> 16) & 1u)) >> 16;
}
__device__ __forceinline__ float bf2f(uint32_t b) { return __uint_as_float(b << 16); }

// ---------------- weight pre-split kernel ----------------
// ws layout (uint16): plane slabs [(mat*3+p)*8 + kk][o 256][32 k] — each
// (plane,kk) slab is a contiguous 16 KB block => main-kernel staging is
// perfectly coalesced. Total 3 mat * 3 planes * 128 KB = 1.125 MB.
__global__ __launch_bounds__(256)
void wsplit_kernel(const float* __restrict__ qw, const float* __restrict__ kw,
                   const float* __restrict__ pw, uint16_t* __restrict__ ws) {
  const int gidx = blockIdx.x * 256 + threadIdx.x;      // 6144 threads
  const int mat = gidx >> 11, kk = (gidx >> 8) & 7, o = gidx & 255;
  const float* w = (mat == 0 ? qw : (mat == 1 ? kw : pw)) + (size_t)o * CC + kk * 32;
  uint16_t hh[32], mm[32], ll[32];
  #pragma unroll
  for (int j = 0; j < 32; ++j) {
    const float v = w[j];
    const uint32_t bh = f2bf(v);
    const float r1 = v - bf2f(bh);       // exact
    const uint32_t bm = f2bf(r1);
    const float r2 = r1 - bf2f(bm);      // exact
    hh[j] = (uint16_t)bh; mm[j] = (uint16_t)bm; ll[j] = (uint16_t)f2bf(r2);
  }
  uint16_t* d0 = ws + (((size_t)(mat * 3 + 0) * 8 + kk) * 256 + o) * 32;
  uint16_t* d1 = ws + (((size_t)(mat * 3 + 1) * 8 + kk) * 256 + o) * 32;
  uint16_t* d2 = ws + (((size_t)(mat * 3 + 2) * 8 + kk) * 256 + o) * 32;
  #pragma unroll
  for (int q = 0; q < 4; ++q) {
    ((uint4*)d0)[q] = ((const uint4*)hh)[q];
    ((uint4*)d1)[q] = ((const uint4*)mm)[q];
    ((uint4*)d2)[q] = ((const uint4*)ll)[q];
  }
}

// ---------------- main kernel ----------------
// LDS map: [0,96K): X planes (3 x 32 KB; [chunk=k>>3][col=t*16+n][8k bf16]).
//          [96K,144K): W slab (3 planes x 16 KB, [row o][32 k]) — also reused
//          as fp32-x staging ([128 c][68 dw], 34.8 KB) during conversion.
#define LDS_XP 0
#define LDS_WS 98304

// LIF (tau=2, hard reset) with decision-margin tracking. h>=th <=> h-th>=0.
__device__ __forceinline__ void lif4m(float q0, float q1, float q2, float q3,
                                      float th, float s[4], float& mg) {
  const float qq[4] = {q0, q1, q2, q3};
  float v = 0.f;
  #pragma unroll
  for (int t = 0; t < 4; ++t) {
    const float h = v + (qq[t] - v) * 0.5f;
    const float d = h - th;
    mg = fminf(mg, fabsf(d));
    const bool f = d >= 0.f;
    s[t] = f ? 1.f : 0.f;
    v = f ? 0.f : h;
  }
}

// One 256x256x64 GEMM via MFMA 16x16x32. NPROD=6: full 3-split product set
// (small->large: wl*xh, wm*xm, wh*xl, wm*xh, wh*xm, wh*xh). NPROD=3: x is
// exact in plane 0 (binary x_one), only w split needed.
template<int NPROD>
__device__ __forceinline__ void gemm_mfma(char* lds, const char* wmat,
                                          int tid, int wv, int ln, int g,
                                          f32x4 acc[4][4]) {
  #pragma unroll
  for (int m = 0; m < 4; ++m)
    #pragma unroll
    for (int nt = 0; nt < 4; ++nt) acc[m][nt] = (f32x4)0.f;

  #pragma unroll 1
  for (int kk = 0; kk < 8; ++kk) {
    __syncthreads();                 // prior slab reads (or conversion) done
    uint4 st[12];                    // stage 48 KB slab, fully coalesced
    #pragma unroll
    for (int i = 0; i < 12; ++i) {
      const int L = i * 4096 + tid * 16;
      const int p = L >> 14, off = L & 16383;
      st[i] = *(const uint4*)(wmat + (size_t)p * 131072 + (size_t)kk * 16384 + off);
    }
    #pragma unroll
    for (int i = 0; i < 12; ++i)
      *(uint4*)(lds + LDS_WS + i * 4096 + tid * 16) = st[i];
    __syncthreads();

    const int BP = (NPROD == 6) ? 3 : 1;
    short8 bf[4][3];
    #pragma unroll
    for (int nt = 0; nt < 4; ++nt)
      #pragma unroll
      for (int p = 0; p < BP; ++p)
        bf[nt][p] = *(const short8*)(lds + LDS_XP + p * 32768 +
                                     (kk * 4 + g) * 1024 + (nt * 16 + ln) * 16);
    #pragma unroll
    for (int m = 0; m < 4; ++m) {
      short8 af[3];
      #pragma unroll
      for (int p = 0; p < 3; ++p)
        af[p] = *(const short8*)(lds + LDS_WS + p * 16384 +
                                 ((wv * 4 + m) * 16 + ln) * 64 + g * 16);
      #pragma unroll
      for (int nt = 0; nt < 4; ++nt) {
        if (NPROD == 6) {
          acc[m][nt] = MFMA(af[2], bf[nt][0], acc[m][nt], 0, 0, 0);
          acc[m][nt] = MFMA(af[1], bf[nt][1], acc[m][nt], 0, 0, 0);
          acc[m][nt] = MFMA(af[0], bf[nt][2], acc[m][nt], 0, 0, 0);
          acc[m][nt] = MFMA(af[1], bf[nt][0], acc[m][nt], 0, 0, 0);
          acc[m][nt] = MFMA(af[0], bf[nt][1], acc[m][nt], 0, 0, 0);
          acc[m][nt] = MFMA(af[0], bf[nt][0], acc[m][nt], 0, 0, 0);
        } else {
          acc[m][nt] = MFMA(af[2], bf[nt][0], acc[m][nt], 0, 0, 0);
          acc[m][nt] = MFMA(af[1], bf[nt][0], acc[m][nt], 0, 0, 0);
          acc[m][nt] = MFMA(af[0], bf[nt][0], acc[m][nt], 0, 0, 0);
        }
      }
    }
  }
}

__global__ __launch_bounds__(256, 1)
void pushpull_mfma(const float* __restrict__ x,
                   const float* __restrict__ q_w, const float* __restrict__ q_gamma,
                   const float* __restrict__ q_beta, const float* __restrict__ q_mean,
                   const float* __restrict__ q_var,
                   const float* __restrict__ k_w, const float* __restrict__ k_gamma,
                   const float* __restrict__ k_beta, const float* __restrict__ k_mean,
                   const float* __restrict__ k_var,
                   const float* __restrict__ proj_w, const float* __restrict__ proj_b,
                   const float* __restrict__ p_gamma, const float* __restrict__ p_beta,
                   const float* __restrict__ p_mean, const float* __restrict__ p_var,
                   const uint16_t* __restrict__ ws, float* __restrict__ out) {
  __shared__ __align__(16) char lds[147456];

  const int tid = threadIdx.x;
  const int bid = (int)blockIdx.x;
  const int lid = ((bid & 7) << 7) | (bid >> 3);  // bijective XCD swizzle (1024=8*128)
  const int b  = lid >> 6;
  const int n0 = (lid & 63) * NT;
  const int ln = tid & 15;          // col-in-tile = spatial n
  const int g  = (tid >> 4) & 3;    // lane group (MFMA k-group / row group)
  const int wv = tid >> 6;          // wave = 64 output channels = 2 heads

  // ---- stage fp32 x + split-convert to 3 bf16 planes (2 half-passes) ----
  float* xf = (float*)(lds + LDS_WS);
  #pragma unroll 1
  for (int hb = 0; hb < 2; ++hb) {
    __syncthreads();
    #pragma unroll
    for (int it = 0; it < 8; ++it) {
      const int idx = it * 256 + tid;
      const int cl = idx >> 4, t = (idx >> 2) & 3, n4 = (idx & 3) * 4;
      const int c = hb * 128 + cl;
      const float4 v = *(const float4*)(x + ((size_t)(t * BB + b) * CC + c) * NN + n0 + n4);
      *(float4*)(xf + cl * 68 + t * 16 + n4) = v;
    }
    __syncthreads();
    const int col = tid & 63, cs = tid >> 6;
    #pragma unroll
    for (int i = 0; i < 4; ++i) {
      const int cL = cs * 4 + i;
      uint16_t ph[8], pm[8], pl[8];
      #pragma unroll
      for (int j = 0; j < 8; ++j) {
        const float v = xf[(cL * 8 + j) * 68 + col];
        const uint32_t bh = f2bf(v);
        const float r1 = v - bf2f(bh);
        const uint32_t bm = f2bf(r1);
        const float r2 = r1 - bf2f(bm);
        ph[j] = (uint16_t)bh; pm[j] = (uint16_t)bm; pl[j] = (uint16_t)f2bf(r2);
      }
      const int ca = (hb * 16 + cL) * 1024 + col * 16;
      *(uint4*)(lds + LDS_XP + 0 * 32768 + ca) = *(const uint4*)ph;
      *(uint4*)(lds + LDS_XP + 1 * 32768 + ca) = *(const uint4*)pm;
      *(uint4*)(lds + LDS_XP + 2 * 32768 + ca) = *(const uint4*)pl;
    }
  }

  f32x4 acc[4][4];
  const char* wsB = (const char*)ws;

  // ================= q pass =================
  gemm_mfma<6>(lds, wsB + (size_t)0 * 393216, tid, wv, ln, g, acc);
  float dA[4] = {0, 0, 0, 0}, dB[4] = {0, 0, 0, 0};
  #pragma unroll
  for (int m = 0; m < 4; ++m) {
    const int ob = (wv * 4 + m) * 16 + g * 4;
    #pragma unroll
    for (int r = 0; r < 4; ++r) {
      const int o = ob + r;
      const float inv = q_gamma[o] / sqrtf(q_var[o] + EPSF);
      const float mn = q_mean[o], bt = q_beta[o];
      float qv[4];
      #pragma unroll
      for (int nt = 0; nt < 4; ++nt) qv[nt] = (acc[m][nt][r] - mn) * inv + bt;
      float se[4], si[4], mg = 1e30f;
      lif4m(qv[0], qv[1], qv[2], qv[3], 1.0f, se, mg);
      lif4m(-qv[0], -qv[1], -qv[2], -qv[3], 1.0f, si, mg);
      if (mg < EPS_R) {   // near-threshold: recompute with exact R1 chain
        const float* wr = q_w + (size_t)o * CC;
        float qx[4];
        #pragma unroll
        for (int t = 0; t < 4; ++t) {
          const float* xg = x + (size_t)(t * BB + b) * CC * NN + n0 + ln;
          float s_ = 0.f;
          #pragma unroll 1
          for (int c = 0; c < CC; ++c) s_ = fmaf(wr[c], xg[(size_t)c * NN], s_);
          qx[t] = (s_ - mn) * inv + bt;
        }
        float mg2 = 1e30f;
        lif4m(qx[0], qx[1], qx[2], qx[3], 1.0f, se, mg2);
        lif4m(-qx[0], -qx[1], -qx[2], -qx[3], 1.0f, si, mg2);
      }
      #pragma unroll
      for (int t = 0; t < 4; ++t) {
        const float dd = se[t] - si[t];
        if (m < 2) dA[t] += dd; else dB[t] += dd;
      }
    }
  }
  #pragma unroll
  for (int t = 0; t < 4; ++t) {   // head reduce over g-groups (exact ints)
    dA[t] += __shfl_xor(dA[t], 16); dA[t] += __shfl_xor(dA[t], 32);
    dB[t] += __shfl_xor(dB[t], 16); dB[t] += __shfl_xor(dB[t], 32);
  }
  float atA[4], atB[4], mgd = 1e30f;
  lif4m(dA[0], dA[1], dA[2], dA[3], 0.5f, atA, mgd);  // exact dyadics
  lif4m(dB[0], dB[1], dB[2], dB[3], 0.5f, atB, mgd);

  // ================= k pass =================
  gemm_mfma<6>(lds, wsB + (size_t)1 * 393216, tid, wv, ln, g, acc);
  __syncthreads();   // all k-pass X-plane reads done before x_one overwrite
  #pragma unroll
  for (int m = 0; m < 4; ++m) {
    const int ob = (wv * 4 + m) * 16 + g * 4;
    unsigned long long pk[4] = {0, 0, 0, 0};
    #pragma unroll
    for (int r = 0; r < 4; ++r) {
      const int o = ob + r;
      const float inv = k_gamma[o] / sqrtf(k_var[o] + EPSF);
      const float mn = k_mean[o], bt = k_beta[o];
      float kv[4];
      #pragma unroll
      for (int nt = 0; nt < 4; ++nt) kv[nt] = (acc[m][nt][r] - mn) * inv + bt;
      float sk[4], mg = 1e30f;
      lif4m(kv[0], kv[1], kv[2], kv[3], 1.0f, sk, mg);
      if (mg < EPS_R) {
        const float* wr = k_w + (size_t)o * CC;
        float kx[4];
        #pragma unroll
        for (int t = 0; t < 4; ++t) {
          const float* xg = x + (size_t)(t * BB + b) * CC * NN + n0 + ln;
          float s_ = 0.f;
          #pragma unroll 1
          for (int c = 0; c < CC; ++c) s_ = fmaf(wr[c], xg[(size_t)c * NN], s_);
          kx[t] = (s_ - mn) * inv + bt;
        }
        float mg2 = 1e30f;
        lif4m(kx[0], kx[1], kx[2], kx[3], 1.0f, sk, mg2);
      }
      #pragma unroll
      for (int t = 0; t < 4; ++t)
        if (sk[t] != 0.f && ((m < 2) ? atA[t] : atB[t]) != 0.f)
          pk[t] |= 0x3F80ull << (r * 16);   // bf16(1.0), exact
    }
    // x_one (binary, bf16-exact) into plane 0 for the proj pass
    const int chunk = (wv * 4 + m) * 2 + (g >> 1);
    #pragma unroll
    for (int t = 0; t < 4; ++t)
      *(unsigned long long*)(lds + LDS_XP + chunk * 1024 +
                             (t * 16 + ln) * 16 + (g & 1) * 8) = pk[t];
  }

  // ================= proj pass =================
  gemm_mfma<3>(lds, wsB + (size_t)2 * 393216, tid, wv, ln, g, acc);
  #pragma unroll
  for (int m = 0; m < 4; ++m) {
    const int ob = (wv * 4 + m) * 16 + g * 4;
    #pragma unroll
    for (int r = 0; r < 4; ++r) {
      const int o = ob + r;
      const float inv = p_gamma[o] / sqrtf(p_var[o] + EPSF);
      const float mn = p_mean[o], bt = p_beta[o], pb = proj_b[o];
      float pv[4];
      #pragma unroll
      for (int nt = 0; nt < 4; ++nt)
        pv[nt] = ((acc[m][nt][r] + pb) - mn) * inv + bt;
      float sp[4], mg = 1e30f;
      lif4m(pv[0], pv[1], pv[2], pv[3], 1.0f, sp, mg);
      if (mg < EPS_R) {
        const float* wr = proj_w + (size_t)o * CC;
        float px[4];
        #pragma unroll
        for (int t = 0; t < 4; ++t) {
          const int colb = (t * 16 + ln) * 16;
          float s_ = 0.f;
          #pragma unroll 1
          for (int c = 0; c < CC; ++c) {
            const float xv = bf2f(*(const uint16_t*)(lds + LDS_XP +
                                  (c >> 3) * 1024 + colb + (c & 7) * 2));
            s_ = fmaf(wr[c], xv, s_);
          }
          px[t] = ((s_ + pb) - mn) * inv + bt;
        }
        float mg2 = 1e30f;
        lif4m(px[0], px[1], px[2], px[3], 1.0f, sp, mg2);
      }
      #pragma unroll
      for (int t = 0; t < 4; ++t)
        out[((size_t)(t * BB + b) * CC + o) * NN + n0 + ln] = sp[t];
    }
  }
}

extern "C" void kernel_launch(void* const* d_in, const int* in_sizes, int n_in,
                              void* d_out, int out_size, void* d_ws, size_t ws_size,
                              hipStream_t stream) {
  const float* x       = (const float*)d_in[0];
  const float* q_w     = (const float*)d_in[1];
  const float* q_gamma = (const float*)d_in[2];
  const float* q_beta  = (const float*)d_in[3];
  const float* q_mean  = (const float*)d_in[4];
  const float* q_var   = (const float*)d_in[5];
  const float* k_w     = (const float*)d_in[6];
  const float* k_gamma = (const float*)d_in[7];
  const float* k_beta  = (const float*)d_in[8];
  const float* k_mean  = (const float*)d_in[9];
  const float* k_var   = (const float*)d_in[10];
  const float* proj_w  = (const float*)d_in[11];
  const float* proj_b  = (const float*)d_in[12];
  const float* p_gamma = (const float*)d_in[13];
  const float* p_beta  = (const float*)d_in[14];
  const float* p_mean  = (const float*)d_in[15];
  const float* p_var   = (const float*)d_in[16];
  float* out = (float*)d_out;
  uint16_t* wsp = (uint16_t*)d_ws;   // 1.125 MB of split-weight planes

  wsplit_kernel<<<24, 256, 0, stream>>>(q_w, k_w, proj_w, wsp);
  pushpull_mfma<<<BB * (NN / NT), 256, 0, stream>>>(
      x, q_w, q_gamma, q_beta, q_mean, q_var,
      k_w, k_gamma, k_beta, k_mean, k_var,
      proj_w, proj_b, p_gamma, p_beta, p_mean, p_var, wsp, out);
}

// Round 9
// 400.455 us; speedup vs baseline: 6.2641x; 6.2641x over previous
//
#include <hip/hip_runtime.h>
#include <math.h>
#include <stdint.h>

// Problem constants
#define TT 4
#define BB 16
#define CC 256
#define NN 1024
#define NT 16        // spatial positions per block
#define EPSF 1e-5f
#define EPS_R 1e-5f  // rescue margin; 6-product GEMM error ~1e-6 (10x safety)

typedef __attribute__((ext_vector_type(8))) short short8;  // 8 bf16 (4 VGPR)
typedef __attribute__((ext_vector_type(4))) float f32x4;
#define MFMA __builtin_amdgcn_mfma_f32_16x16x32_bf16

// LDS geometry (total 148992 B)
#define XCH 1040          // X-plane chunk stride (bytes): 1024 + 16 bank-shift
#define XPL 33280         // X plane = 32 chunks * 1040
#define WPL 16384         // W plane (fragment layout [fr 16][lane 64][16B])
#define LDS_X 0           // 3 X planes: 99840
#define LDS_W 99840       // 3 W planes: 49152
#define LDS_TOT 148992

// bf16 split helpers (RNE). v == hi + mid + lo EXACTLY (3x8 = 24 mantissa bits;
// each residual is exactly representable, normals only for N(0,1)-scale data).
__device__ __forceinline__ uint32_t f2bf(float x) {
  const uint32_t u = __float_as_uint(x);
  return (u + 0x7FFFu + ((u >> 16) & 1u)) >> 16;
}
__device__ __forceinline__ float bf2f(uint32_t b) { return __uint_as_float(b << 16); }

// ---------------- weight pre-split kernel (layout identical to R8) ----------
// ws[(mat*3+p)*8 + kk][o 256][32 k] bf16 — each (plane,kk) slab = 16 KB.
__global__ __launch_bounds__(256)
void wsplit_kernel(const float* __restrict__ qw, const float* __restrict__ kw,
                   const float* __restrict__ pw, uint16_t* __restrict__ ws) {
  const int gidx = blockIdx.x * 256 + threadIdx.x;      // 6144 threads
  const int mat = gidx >> 11, kk = (gidx >> 8) & 7, o = gidx & 255;
  const float* w = (mat == 0 ? qw : (mat == 1 ? kw : pw)) + (size_t)o * CC + kk * 32;
  uint16_t hh[32], mm[32], ll[32];
  #pragma unroll
  for (int j = 0; j < 32; ++j) {
    const float v = w[j];
    const uint32_t bh = f2bf(v);
    const float r1 = v - bf2f(bh);       // exact
    const uint32_t bm = f2bf(r1);
    const float r2 = r1 - bf2f(bm);      // exact
    hh[j] = (uint16_t)bh; mm[j] = (uint16_t)bm; ll[j] = (uint16_t)f2bf(r2);
  }
  uint16_t* d0 = ws + (((size_t)(mat * 3 + 0) * 8 + kk) * 256 + o) * 32;
  uint16_t* d1 = ws + (((size_t)(mat * 3 + 1) * 8 + kk) * 256 + o) * 32;
  uint16_t* d2 = ws + (((size_t)(mat * 3 + 2) * 8 + kk) * 256 + o) * 32;
  #pragma unroll
  for (int q = 0; q < 4; ++q) {
    ((uint4*)d0)[q] = ((const uint4*)hh)[q];
    ((uint4*)d1)[q] = ((const uint4*)mm)[q];
    ((uint4*)d2)[q] = ((const uint4*)ll)[q];
  }
}

// LIF (tau=2, hard reset) with decision-margin tracking.
__device__ __forceinline__ void lif4m(float q0, float q1, float q2, float q3,
                                      float th, float s[4], float& mg) {
  const float qq[4] = {q0, q1, q2, q3};
  float v = 0.f;
  #pragma unroll
  for (int t = 0; t < 4; ++t) {
    const float h = v + (qq[t] - v) * 0.5f;
    const float d = h - th;
    mg = fminf(mg, fabsf(d));
    const bool f = d >= 0.f;
    s[t] = f ? 1.f : 0.f;
    v = f ? 0.f : h;
  }
}

// Exact-chain rescue (q/k): x reconstructed exactly from the 3 LDS planes;
// strict ascending-c fmaf chain per t — bit-identical to the R1 reference
// chain (validated through R8). Exec-masked, rare (P ~ 0.6% per branch).
__device__ __forceinline__ void rescue3(const float* __restrict__ wrow,
                                        const char* lds, int ln, float sv[4]) {
  #pragma unroll
  for (int t = 0; t < 4; ++t) sv[t] = 0.f;
  #pragma unroll 1
  for (int c8 = 0; c8 < 32; ++c8) {
    const float4 wa = *(const float4*)(wrow + c8 * 8);
    const float4 wb = *(const float4*)(wrow + c8 * 8 + 4);
    const float wl_[8] = {wa.x, wa.y, wa.z, wa.w, wb.x, wb.y, wb.z, wb.w};
    #pragma unroll
    for (int t = 0; t < 4; ++t) {
      const int off = c8 * XCH + (t * 16 + ln) * 16;
      const short8 h = *(const short8*)(lds + LDS_X + 0 * XPL + off);
      const short8 m = *(const short8*)(lds + LDS_X + 1 * XPL + off);
      const short8 l = *(const short8*)(lds + LDS_X + 2 * XPL + off);
      float s = sv[t];
      #pragma unroll
      for (int j = 0; j < 8; ++j) {
        const float xv = (bf2f((uint16_t)h[j]) + bf2f((uint16_t)m[j])) +
                         bf2f((uint16_t)l[j]);
        s = fmaf(wl_[j], xv, s);
      }
      sv[t] = s;
    }
  }
}

// Exact-chain rescue (proj): x_one is binary, exact in plane 0.
__device__ __forceinline__ void rescue1(const float* __restrict__ wrow,
                                        const char* lds, int ln, float sv[4]) {
  #pragma unroll
  for (int t = 0; t < 4; ++t) sv[t] = 0.f;
  #pragma unroll 1
  for (int c8 = 0; c8 < 32; ++c8) {
    const float4 wa = *(const float4*)(wrow + c8 * 8);
    const float4 wb = *(const float4*)(wrow + c8 * 8 + 4);
    const float wl_[8] = {wa.x, wa.y, wa.z, wa.w, wb.x, wb.y, wb.z, wb.w};
    #pragma unroll
    for (int t = 0; t < 4; ++t) {
      const int off = c8 * XCH + (t * 16 + ln) * 16;
      const short8 h = *(const short8*)(lds + LDS_X + off);
      float s = sv[t];
      #pragma unroll
      for (int j = 0; j < 8; ++j)
        s = fmaf(wl_[j], bf2f((uint16_t)h[j]), s);
      sv[t] = s;
    }
  }
}

// One 256x256x64 GEMM pass. W slab (32 k) staged per kk into LDS in MFMA
// fragment layout [plane][fr][lane][16B] (conflict-free, aligned reads);
// next slab prefetched to registers BEFORE the MFMA cluster (T14 overlap).
// NPROD=6: hh,hm,mh,mm,hl,lh (small->large, as R8). NPROD=3: binary x.
template<int NPROD>
__device__ __forceinline__ void gemm_pass(char* lds, const char* wmat,
                                          int tid, int wv, int ln, int g,
                                          f32x4 acc[2][4]) {
  const int lane = tid & 63;
  #pragma unroll
  for (int m = 0; m < 2; ++m)
    #pragma unroll
    for (int nt = 0; nt < 4; ++nt) acc[m][nt] = (f32x4)0.f;

  uint4 st[6];
  __syncthreads();                 // prior users of W region / planes done
  #pragma unroll
  for (int i = 0; i < 6; ++i) {    // stage kk=0: frag layout gather
    const int u = i * 512 + tid;
    const int p = u >> 10, fr = (u >> 6) & 15, l = u & 63;
    st[i] = *(const uint4*)(wmat + (size_t)(p * 8 + 0) * 16384 +
                            (fr * 16 + (l & 15)) * 64 + (l >> 4) * 16);
  }
  #pragma unroll
  for (int i = 0; i < 6; ++i) {
    const int u = i * 512 + tid;
    const int p = u >> 10, fr = (u >> 6) & 15, l = u & 63;
    *(uint4*)(lds + LDS_W + p * WPL + fr * 1024 + l * 16) = st[i];
  }
  __syncthreads();

  #pragma unroll 1
  for (int kk = 0; kk < 8; ++kk) {
    if (kk < 7) {                  // prefetch next slab into registers
      #pragma unroll
      for (int i = 0; i < 6; ++i) {
        const int u = i * 512 + tid;
        const int p = u >> 10, fr = (u >> 6) & 15, l = u & 63;
        st[i] = *(const uint4*)(wmat + (size_t)(p * 8 + kk + 1) * 16384 +
                                (fr * 16 + (l & 15)) * 64 + (l >> 4) * 16);
      }
    }
    const int BP = (NPROD == 6) ? 3 : 1;
    short8 bf[4][3];
    #pragma unroll
    for (int nt = 0; nt < 4; ++nt)
      #pragma unroll
      for (int p = 0; p < BP; ++p)
        bf[nt][p] = *(const short8*)(lds + LDS_X + p * XPL +
                                     (kk * 4 + g) * XCH + (nt * 16 + ln) * 16);
    #pragma unroll
    for (int m = 0; m < 2; ++m) {
      short8 af[3];
      #pragma unroll
      for (int p = 0; p < 3; ++p)
        af[p] = *(const short8*)(lds + LDS_W + p * WPL +
                                 (wv * 2 + m) * 1024 + lane * 16);
      #pragma unroll
      for (int nt = 0; nt < 4; ++nt) {
        if (NPROD == 6) {
          acc[m][nt] = MFMA(af[2], bf[nt][0], acc[m][nt], 0, 0, 0);
          acc[m][nt] = MFMA(af[1], bf[nt][1], acc[m][nt], 0, 0, 0);
          acc[m][nt] = MFMA(af[0], bf[nt][2], acc[m][nt], 0, 0, 0);
          acc[m][nt] = MFMA(af[1], bf[nt][0], acc[m][nt], 0, 0, 0);
          acc[m][nt] = MFMA(af[0], bf[nt][1], acc[m][nt], 0, 0, 0);
          acc[m][nt] = MFMA(af[0], bf[nt][0], acc[m][nt], 0, 0, 0);
        } else {
          acc[m][nt] = MFMA(af[2], bf[nt][0], acc[m][nt], 0, 0, 0);
          acc[m][nt] = MFMA(af[1], bf[nt][0], acc[m][nt], 0, 0, 0);
          acc[m][nt] = MFMA(af[0], bf[nt][0], acc[m][nt], 0, 0, 0);
        }
      }
    }
    __syncthreads();               // all reads of slab kk done
    if (kk < 7) {
      #pragma unroll
      for (int i = 0; i < 6; ++i) {
        const int u = i * 512 + tid;
        const int p = u >> 10, fr = (u >> 6) & 15, l = u & 63;
        *(uint4*)(lds + LDS_W + p * WPL + fr * 1024 + l * 16) = st[i];
      }
      __syncthreads();             // slab kk+1 visible
    }
  }
}

// 512 thr = 8 waves; wave = 1 head (32 ch). acc frag: o = wv*32+m*16+g*4+r,
// t = nt, n = ln -> LIF needs no shuffles; head-reduce = 2 shfl_xor.
__global__ __launch_bounds__(512, 2)
void pushpull_mfma2(const float* __restrict__ x,
                    const float* __restrict__ q_w, const float* __restrict__ q_gamma,
                    const float* __restrict__ q_beta, const float* __restrict__ q_mean,
                    const float* __restrict__ q_var,
                    const float* __restrict__ k_w, const float* __restrict__ k_gamma,
                    const float* __restrict__ k_beta, const float* __restrict__ k_mean,
                    const float* __restrict__ k_var,
                    const float* __restrict__ proj_w, const float* __restrict__ proj_b,
                    const float* __restrict__ p_gamma, const float* __restrict__ p_beta,
                    const float* __restrict__ p_mean, const float* __restrict__ p_var,
                    const uint16_t* __restrict__ ws, float* __restrict__ out) {
  __shared__ __align__(16) char lds[LDS_TOT];

  const int tid = threadIdx.x;
  const int bid = (int)blockIdx.x;
  const int lid = ((bid & 7) << 7) | (bid >> 3);   // bijective XCD swizzle
  const int b  = lid >> 6;
  const int n0 = (lid & 63) * NT;
  const int ln = tid & 15;
  const int g  = (tid >> 4) & 3;
  const int wv = tid >> 6;

  // ---- stage fp32 x + split-convert to 3 bf16 planes (2 half-passes) ----
  float* xf = (float*)(lds + LDS_W);   // 34.8 KB scratch in W region
  #pragma unroll 1
  for (int hb = 0; hb < 2; ++hb) {
    __syncthreads();
    #pragma unroll
    for (int it = 0; it < 4; ++it) {
      const int idx = it * 512 + tid;
      const int cl = idx >> 4, t = (idx >> 2) & 3, n4 = (idx & 3) * 4;
      const float4 v = *(const float4*)(
          x + ((size_t)(t * BB + b) * CC + hb * 128 + cl) * NN + n0 + n4);
      *(float4*)(xf + cl * 68 + t * 16 + n4) = v;
    }
    __syncthreads();
    #pragma unroll
    for (int i = 0; i < 2; ++i) {
      const int u = i * 512 + tid;
      const int chL = u >> 6, col = u & 63;
      uint16_t ph[8], pm[8], pl[8];
      #pragma unroll
      for (int j = 0; j < 8; ++j) {
        const float v = xf[(chL * 8 + j) * 68 + col];
        const uint32_t bh = f2bf(v);
        const float r1 = v - bf2f(bh);
        const uint32_t bm = f2bf(r1);
        const float r2 = r1 - bf2f(bm);
        ph[j] = (uint16_t)bh; pm[j] = (uint16_t)bm; pl[j] = (uint16_t)f2bf(r2);
      }
      const int ca = (hb * 16 + chL) * XCH + col * 16;
      *(uint4*)(lds + LDS_X + 0 * XPL + ca) = *(const uint4*)ph;
      *(uint4*)(lds + LDS_X + 1 * XPL + ca) = *(const uint4*)pm;
      *(uint4*)(lds + LDS_X + 2 * XPL + ca) = *(const uint4*)pl;
    }
  }

  f32x4 acc[2][4];
  const char* wsB = (const char*)ws;

  // ================= q pass =================
  gemm_pass<6>(lds, wsB + (size_t)0 * 393216, tid, wv, ln, g, acc);
  float dsum[4] = {0.f, 0.f, 0.f, 0.f};
  #pragma unroll
  for (int m = 0; m < 2; ++m) {
    #pragma unroll
    for (int r = 0; r < 4; ++r) {
      const int o = wv * 32 + m * 16 + g * 4 + r;
      const float inv = q_gamma[o] / sqrtf(q_var[o] + EPSF);
      const float mn = q_mean[o], bt = q_beta[o];
      float qv[4];
      #pragma unroll
      for (int t = 0; t < 4; ++t) qv[t] = (acc[m][t][r] - mn) * inv + bt;
      float se[4], si[4], mg = 1e30f;
      lif4m(qv[0], qv[1], qv[2], qv[3], 1.0f, se, mg);
      lif4m(-qv[0], -qv[1], -qv[2], -qv[3], 1.0f, si, mg);
      if (__builtin_expect(mg < EPS_R, 0)) {
        float qx[4];
        rescue3(q_w + (size_t)o * CC, lds, ln, qx);
        #pragma unroll
        for (int t = 0; t < 4; ++t) qx[t] = (qx[t] - mn) * inv + bt;
        float m2 = 1e30f;
        lif4m(qx[0], qx[1], qx[2], qx[3], 1.0f, se, m2);
        lif4m(-qx[0], -qx[1], -qx[2], -qx[3], 1.0f, si, m2);
      }
      #pragma unroll
      for (int t = 0; t < 4; ++t) dsum[t] += se[t] - si[t];  // exact ints
    }
  }
  float at[4];
  {
    #pragma unroll
    for (int t = 0; t < 4; ++t) {
      float v = dsum[t];
      v += __shfl_xor(v, 16);
      v += __shfl_xor(v, 32);
      dsum[t] = v;                   // exact integer head sums
    }
    float mgd = 1e30f;
    lif4m(dsum[0], dsum[1], dsum[2], dsum[3], 0.5f, at, mgd);  // exact dyadics
  }

  // ================= k pass =================
  gemm_pass<6>(lds, wsB + (size_t)1 * 393216, tid, wv, ln, g, acc);
  unsigned long long pk0[4] = {0, 0, 0, 0}, pk1[4] = {0, 0, 0, 0};
  #pragma unroll
  for (int m = 0; m < 2; ++m) {
    #pragma unroll
    for (int r = 0; r < 4; ++r) {
      const int o = wv * 32 + m * 16 + g * 4 + r;
      const float inv = k_gamma[o] / sqrtf(k_var[o] + EPSF);
      const float mn = k_mean[o], bt = k_beta[o];
      float kv[4];
      #pragma unroll
      for (int t = 0; t < 4; ++t) kv[t] = (acc[m][t][r] - mn) * inv + bt;
      float sk[4], mg = 1e30f;
      lif4m(kv[0], kv[1], kv[2], kv[3], 1.0f, sk, mg);
      if (__builtin_expect(mg < EPS_R, 0)) {
        float kx[4];
        rescue3(k_w + (size_t)o * CC, lds, ln, kx);
        #pragma unroll
        for (int t = 0; t < 4; ++t) kx[t] = (kx[t] - mn) * inv + bt;
        float m2 = 1e30f;
        lif4m(kx[0], kx[1], kx[2], kx[3], 1.0f, sk, m2);
      }
      #pragma unroll
      for (int t = 0; t < 4; ++t) {
        const bool on = (sk[t] != 0.f) && (at[t] != 0.f);
        if (m == 0) pk0[t] |= on ? (0x3F80ull << (r * 16)) : 0ull;
        else        pk1[t] |= on ? (0x3F80ull << (r * 16)) : 0ull;
      }
    }
  }
  __syncthreads();   // all k rescues finished reading X planes
  #pragma unroll
  for (int t = 0; t < 4; ++t) {   // x_one (binary bf16) -> plane 0
    const int base = (t * 16 + ln) * 16 + (g & 1) * 8;
    *(unsigned long long*)(lds + LDS_X + (wv * 4 + 0 + (g >> 1)) * XCH + base) = pk0[t];
    *(unsigned long long*)(lds + LDS_X + (wv * 4 + 2 + (g >> 1)) * XCH + base) = pk1[t];
  }
  // (proj gemm entry barrier makes the writes visible)

  // ================= proj pass =================
  gemm_pass<3>(lds, wsB + (size_t)2 * 393216, tid, wv, ln, g, acc);
  #pragma unroll
  for (int m = 0; m < 2; ++m) {
    #pragma unroll
    for (int r = 0; r < 4; ++r) {
      const int o = wv * 32 + m * 16 + g * 4 + r;
      const float inv = p_gamma[o] / sqrtf(p_var[o] + EPSF);
      const float mn = p_mean[o], bt = p_beta[o], pb = proj_b[o];
      float pv[4];
      #pragma unroll
      for (int t = 0; t < 4; ++t)
        pv[t] = ((acc[m][t][r] + pb) - mn) * inv + bt;
      float sp[4], mg = 1e30f;
      lif4m(pv[0], pv[1], pv[2], pv[3], 1.0f, sp, mg);
      if (__builtin_expect(mg < EPS_R, 0)) {
        float px[4];
        rescue1(proj_w + (size_t)o * CC, lds, ln, px);
        #pragma unroll
        for (int t = 0; t < 4; ++t) px[t] = ((px[t] + pb) - mn) * inv + bt;
        float m2 = 1e30f;
        lif4m(px[0], px[1], px[2], px[3], 1.0f, sp, m2);
      }
      #pragma unroll
      for (int t = 0; t < 4; ++t)
        out[((size_t)(t * BB + b) * CC + o) * NN + n0 + ln] = sp[t];
    }
  }
}

extern "C" void kernel_launch(void* const* d_in, const int* in_sizes, int n_in,
                              void* d_out, int out_size, void* d_ws, size_t ws_size,
                              hipStream_t stream) {
  const float* x       = (const float*)d_in[0];
  const float* q_w     = (const float*)d_in[1];
  const float* q_gamma = (const float*)d_in[2];
  const float* q_beta  = (const float*)d_in[3];
  const float* q_mean  = (const float*)d_in[4];
  const float* q_var   = (const float*)d_in[5];
  const float* k_w     = (const float*)d_in[6];
  const float* k_gamma = (const float*)d_in[7];
  const float* k_beta  = (const float*)d_in[8];
  const float* k_mean  = (const float*)d_in[9];
  const float* k_var   = (const float*)d_in[10];
  const float* proj_w  = (const float*)d_in[11];
  const float* proj_b  = (const float*)d_in[12];
  const float* p_gamma = (const float*)d_in[13];
  const float* p_beta  = (const float*)d_in[14];
  const float* p_mean  = (const float*)d_in[15];
  const float* p_var   = (const float*)d_in[16];
  float* out = (float*)d_out;
  uint16_t* wsp = (uint16_t*)d_ws;   // 1.125 MB split-weight planes

  wsplit_kernel<<<24, 256, 0, stream>>>(q_w, k_w, proj_w, wsp);
  pushpull_mfma2<<<BB * (NN / NT), 512, 0, stream>>>(
      x, q_w, q_gamma, q_beta, q_mean, q_var,
      k_w, k_gamma, k_beta, k_mean, k_var,
      proj_w, proj_b, p_gamma, p_beta, p_mean, p_var, wsp, out);
}

// Round 10
// 168.954 us; speedup vs baseline: 14.8472x; 2.3702x over previous
//
#include <hip/hip_runtime.h>
#include <math.h>
#include <stdint.h>

// Problem constants
#define TT 4
#define BB 16
#define CC 256
#define NN 1024
#define NT 16        // spatial positions per block
#define EPSF 1e-5f
#define EPS_R 1e-5f  // rescue margin; 6-product GEMM error ~1e-6 (10x safety)

typedef __attribute__((ext_vector_type(8))) short short8;  // 8 bf16 (4 VGPR)
typedef __attribute__((ext_vector_type(4))) float f32x4;
#define MFMA __builtin_amdgcn_mfma_f32_16x16x32_bf16

// LDS geometry: 3 X planes + fp32 staging scratch = 134656 B (1 block/CU)
#define XCH 1040          // X-plane chunk stride (bytes): 1024 + 16 bank-shift
#define XPL 33280         // X plane = 32 chunks * 1040
#define LDS_X 0
#define LDS_XF 99840      // fp32 x staging scratch: 128c * 68dw * 4B = 34816
#define LDS_TOT 134656

// bf16 split helpers (RNE). v == hi + mid + lo EXACTLY (3x8 >= 24 mantissa bits).
__device__ __forceinline__ uint32_t f2bf(float x) {
  const uint32_t u = __float_as_uint(x);
  return (u + 0x7FFFu + ((u >> 16) & 1u)) >> 16;
}
__device__ __forceinline__ float bf2f(uint32_t b) { return __uint_as_float(b << 16); }

// ---------------- weight pre-split kernel: fragment-order output ------------
// ws layout (bytes): mat*393216 + p*131072 + ot*8192 + kk*1024 + lane*16.
// Lane l of fragment (ot,kk) holds w_plane[o = ot*16 + (l&15)]
//                                      [k = kk*32 + (l>>4)*8 .. +8]  (bf16 x8)
// => main kernel loads A-fragments DIRECTLY global->VGPR, 1024B/wave-instr.
__global__ __launch_bounds__(256)
void wsplit2(const float* __restrict__ qw, const float* __restrict__ kw,
             const float* __restrict__ pw, uint16_t* __restrict__ ws) {
  const int gid = blockIdx.x * 256 + threadIdx.x;   // 24576 threads
  const int mat = gid >> 13;
  const int ot  = (gid >> 9) & 15;
  const int kk  = (gid >> 6) & 7;
  const int l   = gid & 63;
  const float* w = (mat == 0 ? qw : (mat == 1 ? kw : pw));
  const int o  = ot * 16 + (l & 15);
  const int k0 = kk * 32 + (l >> 4) * 8;
  uint16_t ph[8], pm[8], pl[8];
  #pragma unroll
  for (int j = 0; j < 8; ++j) {
    const float v = w[(size_t)o * CC + k0 + j];
    const uint32_t bh = f2bf(v);
    const float r1 = v - bf2f(bh);       // exact
    const uint32_t bm = f2bf(r1);
    const float r2 = r1 - bf2f(bm);      // exact
    ph[j] = (uint16_t)bh; pm[j] = (uint16_t)bm; pl[j] = (uint16_t)f2bf(r2);
  }
  const size_t base = ((size_t)mat * 3 * 65536) + ((size_t)ot * 4096) +
                      kk * 512 + l * 8;            // uint16 units
  *(uint4*)(ws + base)             = *(const uint4*)ph;
  *(uint4*)(ws + base + 65536)     = *(const uint4*)pm;   // plane stride 128KB
  *(uint4*)(ws + base + 131072)    = *(const uint4*)pl;
}

// LIF (tau=2, hard reset) with decision-margin tracking.
__device__ __forceinline__ void lif4m(float q0, float q1, float q2, float q3,
                                      float th, float s[4], float& mg) {
  const float qq[4] = {q0, q1, q2, q3};
  float v = 0.f;
  #pragma unroll
  for (int t = 0; t < 4; ++t) {
    const float h = v + (qq[t] - v) * 0.5f;
    const float d = h - th;
    mg = fminf(mg, fabsf(d));
    const bool f = d >= 0.f;
    s[t] = f ? 1.f : 0.f;
    v = f ? 0.f : h;
  }
}

// Exact-chain rescue (q/k): x reconstructed exactly from the 3 LDS planes;
// strict ascending-c fmaf chain per t — bit-identical to the validated chain.
__device__ __forceinline__ void rescue3(const float* __restrict__ wrow,
                                        const char* lds, int ln, float sv[4]) {
  #pragma unroll
  for (int t = 0; t < 4; ++t) sv[t] = 0.f;
  #pragma unroll 1
  for (int c8 = 0; c8 < 32; ++c8) {
    const float4 wa = *(const float4*)(wrow + c8 * 8);
    const float4 wb = *(const float4*)(wrow + c8 * 8 + 4);
    const float wl_[8] = {wa.x, wa.y, wa.z, wa.w, wb.x, wb.y, wb.z, wb.w};
    #pragma unroll
    for (int t = 0; t < 4; ++t) {
      const int off = c8 * XCH + (t * 16 + ln) * 16;
      const short8 h = *(const short8*)(lds + LDS_X + 0 * XPL + off);
      const short8 m = *(const short8*)(lds + LDS_X + 1 * XPL + off);
      const short8 l = *(const short8*)(lds + LDS_X + 2 * XPL + off);
      float s = sv[t];
      #pragma unroll
      for (int j = 0; j < 8; ++j) {
        const float xv = (bf2f((uint16_t)h[j]) + bf2f((uint16_t)m[j])) +
                         bf2f((uint16_t)l[j]);
        s = fmaf(wl_[j], xv, s);
      }
      sv[t] = s;
    }
  }
}

// Exact-chain rescue (proj): x_one is binary, exact in plane 0.
__device__ __forceinline__ void rescue1(const float* __restrict__ wrow,
                                        const char* lds, int ln, float sv[4]) {
  #pragma unroll
  for (int t = 0; t < 4; ++t) sv[t] = 0.f;
  #pragma unroll 1
  for (int c8 = 0; c8 < 32; ++c8) {
    const float4 wa = *(const float4*)(wrow + c8 * 8);
    const float4 wb = *(const float4*)(wrow + c8 * 8 + 4);
    const float wl_[8] = {wa.x, wa.y, wa.z, wa.w, wb.x, wb.y, wb.z, wb.w};
    #pragma unroll
    for (int t = 0; t < 4; ++t) {
      const int off = c8 * XCH + (t * 16 + ln) * 16;
      const short8 h = *(const short8*)(lds + LDS_X + off);
      float s = sv[t];
      #pragma unroll
      for (int j = 0; j < 8; ++j)
        s = fmaf(wl_[j], bf2f((uint16_t)h[j]), s);
      sv[t] = s;
    }
  }
}

// One 256x256x64 GEMM pass. NO barriers, NO LDS writes: A-fragments stream
// global->VGPR (contiguous 1024B per wave-instr, L2-resident, vmcnt-
// pipelined); B-fragments via ds_read_b128 from the read-only X planes.
// Product order per accumulator identical to rounds 8/9 (bit-exact).
template<int NPROD>
__device__ __forceinline__ void gemm_pass(const char* lds, const char* wm,
                                          int tid, int wv, int ln, int g,
                                          f32x4 acc[2][4]) {
  const int lane = tid & 63;
  #pragma unroll
  for (int m = 0; m < 2; ++m)
    #pragma unroll
    for (int nt = 0; nt < 4; ++nt) acc[m][nt] = (f32x4)0.f;

  #pragma unroll 1
  for (int kk = 0; kk < 8; ++kk) {
    short8 af0[3], af1[3];
    #pragma unroll
    for (int p = 0; p < 3; ++p) {
      const char* pb = wm + (size_t)p * 131072 + kk * 1024 + lane * 16;
      af0[p] = *(const short8*)(pb + (size_t)(wv * 2 + 0) * 8192);
      af1[p] = *(const short8*)(pb + (size_t)(wv * 2 + 1) * 8192);
    }
    const int BP = (NPROD == 6) ? 3 : 1;
    short8 bf[4][3];
    #pragma unroll
    for (int nt = 0; nt < 4; ++nt)
      #pragma unroll
      for (int p = 0; p < BP; ++p)
        bf[nt][p] = *(const short8*)(lds + LDS_X + p * XPL +
                                     (kk * 4 + g) * XCH + (nt * 16 + ln) * 16);
    #pragma unroll
    for (int nt = 0; nt < 4; ++nt) {
      if (NPROD == 6) {
        acc[0][nt] = MFMA(af0[2], bf[nt][0], acc[0][nt], 0, 0, 0);
        acc[0][nt] = MFMA(af0[1], bf[nt][1], acc[0][nt], 0, 0, 0);
        acc[0][nt] = MFMA(af0[0], bf[nt][2], acc[0][nt], 0, 0, 0);
        acc[0][nt] = MFMA(af0[1], bf[nt][0], acc[0][nt], 0, 0, 0);
        acc[0][nt] = MFMA(af0[0], bf[nt][1], acc[0][nt], 0, 0, 0);
        acc[0][nt] = MFMA(af0[0], bf[nt][0], acc[0][nt], 0, 0, 0);
      } else {
        acc[0][nt] = MFMA(af0[2], bf[nt][0], acc[0][nt], 0, 0, 0);
        acc[0][nt] = MFMA(af0[1], bf[nt][0], acc[0][nt], 0, 0, 0);
        acc[0][nt] = MFMA(af0[0], bf[nt][0], acc[0][nt], 0, 0, 0);
      }
    }
    #pragma unroll
    for (int nt = 0; nt < 4; ++nt) {
      if (NPROD == 6) {
        acc[1][nt] = MFMA(af1[2], bf[nt][0], acc[1][nt], 0, 0, 0);
        acc[1][nt] = MFMA(af1[1], bf[nt][1], acc[1][nt], 0, 0, 0);
        acc[1][nt] = MFMA(af1[0], bf[nt][2], acc[1][nt], 0, 0, 0);
        acc[1][nt] = MFMA(af1[1], bf[nt][0], acc[1][nt], 0, 0, 0);
        acc[1][nt] = MFMA(af1[0], bf[nt][1], acc[1][nt], 0, 0, 0);
        acc[1][nt] = MFMA(af1[0], bf[nt][0], acc[1][nt], 0, 0, 0);
      } else {
        acc[1][nt] = MFMA(af1[2], bf[nt][0], acc[1][nt], 0, 0, 0);
        acc[1][nt] = MFMA(af1[1], bf[nt][0], acc[1][nt], 0, 0, 0);
        acc[1][nt] = MFMA(af1[0], bf[nt][0], acc[1][nt], 0, 0, 0);
      }
    }
  }
}

// 512 thr = 8 waves; wave = 1 head (32 ch): o = wv*32 + m*16 + g*4 + r,
// t = nt, n = ln -> LIF shuffle-free; head-reduce = 2 shfl_xor.
__global__ __launch_bounds__(512, 2)
void pushpull_mfma3(const float* __restrict__ x,
                    const float* __restrict__ q_w, const float* __restrict__ q_gamma,
                    const float* __restrict__ q_beta, const float* __restrict__ q_mean,
                    const float* __restrict__ q_var,
                    const float* __restrict__ k_w, const float* __restrict__ k_gamma,
                    const float* __restrict__ k_beta, const float* __restrict__ k_mean,
                    const float* __restrict__ k_var,
                    const float* __restrict__ proj_w, const float* __restrict__ proj_b,
                    const float* __restrict__ p_gamma, const float* __restrict__ p_beta,
                    const float* __restrict__ p_mean, const float* __restrict__ p_var,
                    const uint16_t* __restrict__ ws, float* __restrict__ out) {
  __shared__ __align__(16) char lds[LDS_TOT];

  const int tid = threadIdx.x;
  const int bid = (int)blockIdx.x;
  const int lid = ((bid & 7) << 7) | (bid >> 3);   // bijective XCD swizzle
  const int b  = lid >> 6;
  const int n0 = (lid & 63) * NT;
  const int ln = tid & 15;
  const int g  = (tid >> 4) & 3;
  const int wv = tid >> 6;

  // ---- stage fp32 x + split-convert to 3 bf16 planes (2 half-passes) ----
  float* xf = (float*)(lds + LDS_XF);
  #pragma unroll 1
  for (int hb = 0; hb < 2; ++hb) {
    __syncthreads();
    #pragma unroll
    for (int it = 0; it < 4; ++it) {
      const int idx = it * 512 + tid;
      const int cl = idx >> 4, t = (idx >> 2) & 3, n4 = (idx & 3) * 4;
      const float4 v = *(const float4*)(
          x + ((size_t)(t * BB + b) * CC + hb * 128 + cl) * NN + n0 + n4);
      *(float4*)(xf + cl * 68 + t * 16 + n4) = v;
    }
    __syncthreads();
    #pragma unroll
    for (int i = 0; i < 2; ++i) {
      const int u = i * 512 + tid;
      const int chL = u >> 6, col = u & 63;
      uint16_t ph[8], pm[8], pl[8];
      #pragma unroll
      for (int j = 0; j < 8; ++j) {
        const float v = xf[(chL * 8 + j) * 68 + col];
        const uint32_t bh = f2bf(v);
        const float r1 = v - bf2f(bh);
        const uint32_t bm = f2bf(r1);
        const float r2 = r1 - bf2f(bm);
        ph[j] = (uint16_t)bh; pm[j] = (uint16_t)bm; pl[j] = (uint16_t)f2bf(r2);
      }
      const int ca = (hb * 16 + chL) * XCH + col * 16;
      *(uint4*)(lds + LDS_X + 0 * XPL + ca) = *(const uint4*)ph;
      *(uint4*)(lds + LDS_X + 1 * XPL + ca) = *(const uint4*)pm;
      *(uint4*)(lds + LDS_X + 2 * XPL + ca) = *(const uint4*)pl;
    }
  }
  __syncthreads();   // all X planes visible to all waves

  f32x4 acc[2][4];
  const char* wsB = (const char*)ws;

  // ================= q pass =================
  gemm_pass<6>(lds, wsB + (size_t)0 * 393216, tid, wv, ln, g, acc);
  float dsum[4] = {0.f, 0.f, 0.f, 0.f};
  #pragma unroll
  for (int m = 0; m < 2; ++m) {
    #pragma unroll
    for (int r = 0; r < 4; ++r) {
      const int o = wv * 32 + m * 16 + g * 4 + r;
      const float inv = q_gamma[o] / sqrtf(q_var[o] + EPSF);
      const float mn = q_mean[o], bt = q_beta[o];
      float qv[4];
      #pragma unroll
      for (int t = 0; t < 4; ++t) qv[t] = (acc[m][t][r] - mn) * inv + bt;
      float se[4], si[4], mg = 1e30f;
      lif4m(qv[0], qv[1], qv[2], qv[3], 1.0f, se, mg);
      lif4m(-qv[0], -qv[1], -qv[2], -qv[3], 1.0f, si, mg);
      if (__builtin_expect(mg < EPS_R, 0)) {
        float qx[4];
        rescue3(q_w + (size_t)o * CC, lds, ln, qx);
        #pragma unroll
        for (int t = 0; t < 4; ++t) qx[t] = (qx[t] - mn) * inv + bt;
        float m2 = 1e30f;
        lif4m(qx[0], qx[1], qx[2], qx[3], 1.0f, se, m2);
        lif4m(-qx[0], -qx[1], -qx[2], -qx[3], 1.0f, si, m2);
      }
      #pragma unroll
      for (int t = 0; t < 4; ++t) dsum[t] += se[t] - si[t];  // exact ints
    }
  }
  float at[4];
  {
    #pragma unroll
    for (int t = 0; t < 4; ++t) {
      float v = dsum[t];
      v += __shfl_xor(v, 16);
      v += __shfl_xor(v, 32);
      dsum[t] = v;                   // exact integer head sums
    }
    float mgd = 1e30f;
    lif4m(dsum[0], dsum[1], dsum[2], dsum[3], 0.5f, at, mgd);  // exact dyadics
  }

  // ================= k pass =================
  gemm_pass<6>(lds, wsB + (size_t)1 * 393216, tid, wv, ln, g, acc);
  unsigned long long pk0[4] = {0, 0, 0, 0}, pk1[4] = {0, 0, 0, 0};
  #pragma unroll
  for (int m = 0; m < 2; ++m) {
    #pragma unroll
    for (int r = 0; r < 4; ++r) {
      const int o = wv * 32 + m * 16 + g * 4 + r;
      const float inv = k_gamma[o] / sqrtf(k_var[o] + EPSF);
      const float mn = k_mean[o], bt = k_beta[o];
      float kv[4];
      #pragma unroll
      for (int t = 0; t < 4; ++t) kv[t] = (acc[m][t][r] - mn) * inv + bt;
      float sk[4], mg = 1e30f;
      lif4m(kv[0], kv[1], kv[2], kv[3], 1.0f, sk, mg);
      if (__builtin_expect(mg < EPS_R, 0)) {
        float kx[4];
        rescue3(k_w + (size_t)o * CC, lds, ln, kx);
        #pragma unroll
        for (int t = 0; t < 4; ++t) kx[t] = (kx[t] - mn) * inv + bt;
        float m2 = 1e30f;
        lif4m(kx[0], kx[1], kx[2], kx[3], 1.0f, sk, m2);
      }
      #pragma unroll
      for (int t = 0; t < 4; ++t) {
        const bool on = (sk[t] != 0.f) && (at[t] != 0.f);
        if (m == 0) pk0[t] |= on ? (0x3F80ull << (r * 16)) : 0ull;
        else        pk1[t] |= on ? (0x3F80ull << (r * 16)) : 0ull;
      }
    }
  }
  __syncthreads();   // all k-pass X-plane reads (incl. rescues) done
  #pragma unroll
  for (int t = 0; t < 4; ++t) {   // x_one (binary bf16) -> plane 0
    const int base = (t * 16 + ln) * 16 + (g & 1) * 8;
    *(unsigned long long*)(lds + LDS_X + (wv * 4 + 0 + (g >> 1)) * XCH + base) = pk0[t];
    *(unsigned long long*)(lds + LDS_X + (wv * 4 + 2 + (g >> 1)) * XCH + base) = pk1[t];
  }
  __syncthreads();   // x_one visible

  // ================= proj pass =================
  gemm_pass<3>(lds, wsB + (size_t)2 * 393216, tid, wv, ln, g, acc);
  #pragma unroll
  for (int m = 0; m < 2; ++m) {
    #pragma unroll
    for (int r = 0; r < 4; ++r) {
      const int o = wv * 32 + m * 16 + g * 4 + r;
      const float inv = p_gamma[o] / sqrtf(p_var[o] + EPSF);
      const float mn = p_mean[o], bt = p_beta[o], pb = proj_b[o];
      float pv[4];
      #pragma unroll
      for (int t = 0; t < 4; ++t)
        pv[t] = ((acc[m][t][r] + pb) - mn) * inv + bt;
      float sp[4], mg = 1e30f;
      lif4m(pv[0], pv[1], pv[2], pv[3], 1.0f, sp, mg);
      if (__builtin_expect(mg < EPS_R, 0)) {
        float px[4];
        rescue1(proj_w + (size_t)o * CC, lds, ln, px);
        #pragma unroll
        for (int t = 0; t < 4; ++t) px[t] = ((px[t] + pb) - mn) * inv + bt;
        float m2 = 1e30f;
        lif4m(px[0], px[1], px[2], px[3], 1.0f, sp, m2);
      }
      #pragma unroll
      for (int t = 0; t < 4; ++t)
        out[((size_t)(t * BB + b) * CC + o) * NN + n0 + ln] = sp[t];
    }
  }
}

extern "C" void kernel_launch(void* const* d_in, const int* in_sizes, int n_in,
                              void* d_out, int out_size, void* d_ws, size_t ws_size,
                              hipStream_t stream) {
  const float* x       = (const float*)d_in[0];
  const float* q_w     = (const float*)d_in[1];
  const float* q_gamma = (const float*)d_in[2];
  const float* q_beta  = (const float*)d_in[3];
  const float* q_mean  = (const float*)d_in[4];
  const float* q_var   = (const float*)d_in[5];
  const float* k_w     = (const float*)d_in[6];
  const float* k_gamma = (const float*)d_in[7];
  const float* k_beta  = (const float*)d_in[8];
  const float* k_mean  = (const float*)d_in[9];
  const float* k_var   = (const float*)d_in[10];
  const float* proj_w  = (const float*)d_in[11];
  const float* proj_b  = (const float*)d_in[12];
  const float* p_gamma = (const float*)d_in[13];
  const float* p_beta  = (const float*)d_in[14];
  const float* p_mean  = (const float*)d_in[15];
  const float* p_var   = (const float*)d_in[16];
  float* out = (float*)d_out;
  uint16_t* wsp = (uint16_t*)d_ws;   // 1.125 MB split-weight fragment planes

  wsplit2<<<96, 256, 0, stream>>>(q_w, k_w, proj_w, wsp);
  pushpull_mfma3<<<BB * (NN / NT), 512, 0, stream>>>(
      x, q_w, q_gamma, q_beta, q_mean, q_var,
      k_w, k_gamma, k_beta, k_mean, k_var,
      proj_w, proj_b, p_gamma, p_beta, p_mean, p_var, wsp, out);
}

// Round 11
// 155.403 us; speedup vs baseline: 16.1419x; 1.0872x over previous
//
#include <hip/hip_runtime.h>
#include <math.h>
#include <stdint.h>

// Problem constants
#define TT 4
#define BB 16
#define CC 256
#define NN 1024
#define NT 16        // spatial positions per block
#define EPSF 1e-5f
#define EPS_R 1e-5f  // rescue margin; 6-product GEMM error ~1e-6 (10x safety)

typedef __attribute__((ext_vector_type(8))) short short8;  // 8 bf16 (4 VGPR)
typedef __attribute__((ext_vector_type(4))) float f32x4;
#define MFMA __builtin_amdgcn_mfma_f32_16x16x32_bf16

// LDS geometry: 3 X planes + fp32 staging scratch = 134656 B (1 block/CU)
#define XCH 1040          // X-plane chunk stride (bytes): 1024 + 16 bank-shift
#define XPL 33280         // X plane = 32 chunks * 1040
#define LDS_X 0
#define LDS_XF 99840      // fp32 x scratch (128c * 68dw * 4B) / dsum exchange
#define LDS_TOT 134656

// bf16 split helpers (RNE). v == hi + mid + lo EXACTLY (3x8 >= 24 mantissa bits).
__device__ __forceinline__ uint32_t f2bf(float x) {
  const uint32_t u = __float_as_uint(x);
  return (u + 0x7FFFu + ((u >> 16) & 1u)) >> 16;
}
__device__ __forceinline__ float bf2f(uint32_t b) { return __uint_as_float(b << 16); }

// ---------------- weight pre-split kernel (identical to R10) ----------------
// ws bytes: mat*393216 + p*131072 + ot*8192 + kk*1024 + lane*16.
// Lane l: w_plane[o = ot*16 + (l&15)][k = kk*32 + (l>>4)*8 .. +8]
__global__ __launch_bounds__(256)
void wsplit2(const float* __restrict__ qw, const float* __restrict__ kw,
             const float* __restrict__ pw, uint16_t* __restrict__ ws) {
  const int gid = blockIdx.x * 256 + threadIdx.x;   // 24576 threads
  const int mat = gid >> 13;
  const int ot  = (gid >> 9) & 15;
  const int kk  = (gid >> 6) & 7;
  const int l   = gid & 63;
  const float* w = (mat == 0 ? qw : (mat == 1 ? kw : pw));
  const int o  = ot * 16 + (l & 15);
  const int k0 = kk * 32 + (l >> 4) * 8;
  uint16_t ph[8], pm[8], pl[8];
  #pragma unroll
  for (int j = 0; j < 8; ++j) {
    const float v = w[(size_t)o * CC + k0 + j];
    const uint32_t bh = f2bf(v);
    const float r1 = v - bf2f(bh);       // exact
    const uint32_t bm = f2bf(r1);
    const float r2 = r1 - bf2f(bm);      // exact
    ph[j] = (uint16_t)bh; pm[j] = (uint16_t)bm; pl[j] = (uint16_t)f2bf(r2);
  }
  const size_t base = ((size_t)mat * 3 * 65536) + ((size_t)ot * 4096) +
                      kk * 512 + l * 8;            // uint16 units
  *(uint4*)(ws + base)          = *(const uint4*)ph;
  *(uint4*)(ws + base + 65536)  = *(const uint4*)pm;   // plane stride 128KB
  *(uint4*)(ws + base + 131072) = *(const uint4*)pl;
}

// LIF (tau=2, hard reset) with decision-margin tracking.
__device__ __forceinline__ void lif4m(float q0, float q1, float q2, float q3,
                                      float th, float s[4], float& mg) {
  const float qq[4] = {q0, q1, q2, q3};
  float v = 0.f;
  #pragma unroll
  for (int t = 0; t < 4; ++t) {
    const float h = v + (qq[t] - v) * 0.5f;
    const float d = h - th;
    mg = fminf(mg, fabsf(d));
    const bool f = d >= 0.f;
    s[t] = f ? 1.f : 0.f;
    v = f ? 0.f : h;
  }
}

// Exact-chain rescue (q/k): x reconstructed exactly from the 3 LDS planes;
// strict ascending-c fmaf chain per t — bit-identical to the validated chain.
__device__ __forceinline__ void rescue3(const float* __restrict__ wrow,
                                        const char* lds, int ln, float sv[4]) {
  #pragma unroll
  for (int t = 0; t < 4; ++t) sv[t] = 0.f;
  #pragma unroll 1
  for (int c8 = 0; c8 < 32; ++c8) {
    const float4 wa = *(const float4*)(wrow + c8 * 8);
    const float4 wb = *(const float4*)(wrow + c8 * 8 + 4);
    const float wl_[8] = {wa.x, wa.y, wa.z, wa.w, wb.x, wb.y, wb.z, wb.w};
    #pragma unroll
    for (int t = 0; t < 4; ++t) {
      const int off = c8 * XCH + (t * 16 + ln) * 16;
      const short8 h = *(const short8*)(lds + LDS_X + 0 * XPL + off);
      const short8 m = *(const short8*)(lds + LDS_X + 1 * XPL + off);
      const short8 l = *(const short8*)(lds + LDS_X + 2 * XPL + off);
      float s = sv[t];
      #pragma unroll
      for (int j = 0; j < 8; ++j) {
        const float xv = (bf2f((uint16_t)h[j]) + bf2f((uint16_t)m[j])) +
                         bf2f((uint16_t)l[j]);
        s = fmaf(wl_[j], xv, s);
      }
      sv[t] = s;
    }
  }
}

// Exact-chain rescue (proj): x_one is binary, exact in plane 0.
__device__ __forceinline__ void rescue1(const float* __restrict__ wrow,
                                        const char* lds, int ln, float sv[4]) {
  #pragma unroll
  for (int t = 0; t < 4; ++t) sv[t] = 0.f;
  #pragma unroll 1
  for (int c8 = 0; c8 < 32; ++c8) {
    const float4 wa = *(const float4*)(wrow + c8 * 8);
    const float4 wb = *(const float4*)(wrow + c8 * 8 + 4);
    const float wl_[8] = {wa.x, wa.y, wa.z, wa.w, wb.x, wb.y, wb.z, wb.w};
    #pragma unroll
    for (int t = 0; t < 4; ++t) {
      const int off = c8 * XCH + (t * 16 + ln) * 16;
      const short8 h = *(const short8*)(lds + LDS_X + off);
      float s = sv[t];
      #pragma unroll
      for (int j = 0; j < 8; ++j)
        s = fmaf(wl_[j], bf2f((uint16_t)h[j]), s);
      sv[t] = s;
    }
  }
}

// 1024 thr = 16 waves (4/SIMD); wave = one 16-channel o-tile (ot).
// acc[nt][r]: o = ot*16 + g*4 + r, t = nt, n = ln -> LIF shuffle-free.
// Head h = waves {2h, 2h+1}; dsum pair-reduce via LDS exchange.
__global__ __launch_bounds__(1024, 4)
void pushpull_mfma4(const float* __restrict__ x,
                    const float* __restrict__ q_w, const float* __restrict__ q_gamma,
                    const float* __restrict__ q_beta, const float* __restrict__ q_mean,
                    const float* __restrict__ q_var,
                    const float* __restrict__ k_w, const float* __restrict__ k_gamma,
                    const float* __restrict__ k_beta, const float* __restrict__ k_mean,
                    const float* __restrict__ k_var,
                    const float* __restrict__ proj_w, const float* __restrict__ proj_b,
                    const float* __restrict__ p_gamma, const float* __restrict__ p_beta,
                    const float* __restrict__ p_mean, const float* __restrict__ p_var,
                    const uint16_t* __restrict__ ws, float* __restrict__ out) {
  __shared__ __align__(16) char lds[LDS_TOT];

  const int tid  = threadIdx.x;
  const int bid  = (int)blockIdx.x;
  const int lid  = ((bid & 7) << 7) | (bid >> 3);   // bijective XCD swizzle
  const int b    = lid >> 6;
  const int n0   = (lid & 63) * NT;
  const int lane = tid & 63;
  const int ln   = tid & 15;
  const int g    = (tid >> 4) & 3;
  const int ot   = tid >> 6;           // wave index = o-tile (16 channels)

  // ---- stage fp32 x + split-convert to 3 bf16 planes (2 half-passes) ----
  float* xf = (float*)(lds + LDS_XF);
  #pragma unroll 1
  for (int hb = 0; hb < 2; ++hb) {
    #pragma unroll
    for (int it = 0; it < 2; ++it) {
      const int idx = it * 1024 + tid;
      const int n4 = (idx & 3) * 4, t = (idx >> 2) & 3, cl = idx >> 4;
      const float4 v = *(const float4*)(
          x + ((size_t)(t * BB + b) * CC + hb * 128 + cl) * NN + n0 + n4);
      *(float4*)(xf + cl * 68 + t * 16 + n4) = v;
    }
    __syncthreads();
    {
      const int chL = tid >> 6, col = tid & 63;   // 16 chunks x 64 cols
      uint16_t ph[8], pm[8], pl[8];
      #pragma unroll
      for (int j = 0; j < 8; ++j) {
        const float v = xf[(chL * 8 + j) * 68 + col];
        const uint32_t bh = f2bf(v);
        const float r1 = v - bf2f(bh);
        const uint32_t bm = f2bf(r1);
        const float r2 = r1 - bf2f(bm);
        ph[j] = (uint16_t)bh; pm[j] = (uint16_t)bm; pl[j] = (uint16_t)f2bf(r2);
      }
      const int ca = (hb * 16 + chL) * XCH + col * 16;
      *(uint4*)(lds + LDS_X + 0 * XPL + ca) = *(const uint4*)ph;
      *(uint4*)(lds + LDS_X + 1 * XPL + ca) = *(const uint4*)pm;
      *(uint4*)(lds + LDS_X + 2 * XPL + ca) = *(const uint4*)pl;
    }
    __syncthreads();
  }

  const char* wq = (const char*)ws;                       // q planes
  const char* wk = (const char*)ws + 393216;              // k planes
  const char* wp = (const char*)ws + 786432;              // proj planes

  // ================= fused q + k GEMM (shared bf reads) =================
  f32x4 aq[4], ak[4];
  #pragma unroll
  for (int nt = 0; nt < 4; ++nt) { aq[nt] = (f32x4)0.f; ak[nt] = (f32x4)0.f; }
  #pragma unroll 1
  for (int kk = 0; kk < 8; ++kk) {
    short8 fq[3], fk[3];
    #pragma unroll
    for (int p = 0; p < 3; ++p) {
      const size_t foff = (size_t)p * 131072 + (size_t)ot * 8192 + kk * 1024 + lane * 16;
      fq[p] = *(const short8*)(wq + foff);
      fk[p] = *(const short8*)(wk + foff);
    }
    #pragma unroll
    for (int nt = 0; nt < 4; ++nt) {
      const int boff = (kk * 4 + g) * XCH + (nt * 16 + ln) * 16;
      const short8 b0 = *(const short8*)(lds + LDS_X + 0 * XPL + boff);
      const short8 b1 = *(const short8*)(lds + LDS_X + 1 * XPL + boff);
      const short8 b2 = *(const short8*)(lds + LDS_X + 2 * XPL + boff);
      // product order per accumulator identical to R8-R10 (bit-exact)
      aq[nt] = MFMA(fq[2], b0, aq[nt], 0, 0, 0);
      aq[nt] = MFMA(fq[1], b1, aq[nt], 0, 0, 0);
      aq[nt] = MFMA(fq[0], b2, aq[nt], 0, 0, 0);
      aq[nt] = MFMA(fq[1], b0, aq[nt], 0, 0, 0);
      aq[nt] = MFMA(fq[0], b1, aq[nt], 0, 0, 0);
      aq[nt] = MFMA(fq[0], b0, aq[nt], 0, 0, 0);
      ak[nt] = MFMA(fk[2], b0, ak[nt], 0, 0, 0);
      ak[nt] = MFMA(fk[1], b1, ak[nt], 0, 0, 0);
      ak[nt] = MFMA(fk[0], b2, ak[nt], 0, 0, 0);
      ak[nt] = MFMA(fk[1], b0, ak[nt], 0, 0, 0);
      ak[nt] = MFMA(fk[0], b1, ak[nt], 0, 0, 0);
      ak[nt] = MFMA(fk[0], b0, ak[nt], 0, 0, 0);
    }
  }

  // ---- q epilogue: BN + push/pull LIF (+rescue) -> dsum[t] ----
  float dsum[4] = {0.f, 0.f, 0.f, 0.f};
  #pragma unroll
  for (int r = 0; r < 4; ++r) {
    const int o = ot * 16 + g * 4 + r;
    const float inv = q_gamma[o] / sqrtf(q_var[o] + EPSF);
    const float mn = q_mean[o], bt = q_beta[o];
    float qv[4];
    #pragma unroll
    for (int t = 0; t < 4; ++t) qv[t] = (aq[t][r] - mn) * inv + bt;
    float se[4], si[4], mg = 1e30f;
    lif4m(qv[0], qv[1], qv[2], qv[3], 1.0f, se, mg);
    lif4m(-qv[0], -qv[1], -qv[2], -qv[3], 1.0f, si, mg);
    if (__builtin_expect(mg < EPS_R, 0)) {
      float qx[4];
      rescue3(q_w + (size_t)o * CC, lds, ln, qx);
      #pragma unroll
      for (int t = 0; t < 4; ++t) qx[t] = (qx[t] - mn) * inv + bt;
      float m2 = 1e30f;
      lif4m(qx[0], qx[1], qx[2], qx[3], 1.0f, se, m2);
      lif4m(-qx[0], -qx[1], -qx[2], -qx[3], 1.0f, si, m2);
    }
    #pragma unroll
    for (int t = 0; t < 4; ++t) dsum[t] += se[t] - si[t];   // exact ints
  }
  // reduce over the wave's 4 g-groups (16 channels), exact ints
  #pragma unroll
  for (int t = 0; t < 4; ++t) {
    float v = dsum[t];
    v += __shfl_xor(v, 16);
    v += __shfl_xor(v, 32);
    dsum[t] = v;
  }

  // ---- k epilogue: BN + LIF (+rescue) -> spike bits ----
  unsigned kb = 0u;   // bit r*4+t
  #pragma unroll
  for (int r = 0; r < 4; ++r) {
    const int o = ot * 16 + g * 4 + r;
    const float inv = k_gamma[o] / sqrtf(k_var[o] + EPSF);
    const float mn = k_mean[o], bt = k_beta[o];
    float kv[4];
    #pragma unroll
    for (int t = 0; t < 4; ++t) kv[t] = (ak[t][r] - mn) * inv + bt;
    float sk[4], mg = 1e30f;
    lif4m(kv[0], kv[1], kv[2], kv[3], 1.0f, sk, mg);
    if (__builtin_expect(mg < EPS_R, 0)) {
      float kx[4];
      rescue3(k_w + (size_t)o * CC, lds, ln, kx);
      #pragma unroll
      for (int t = 0; t < 4; ++t) kx[t] = (kx[t] - mn) * inv + bt;
      float m2 = 1e30f;
      lif4m(kx[0], kx[1], kx[2], kx[3], 1.0f, sk, m2);
    }
    #pragma unroll
    for (int t = 0; t < 4; ++t) kb |= (sk[t] != 0.f) ? (1u << (r * 4 + t)) : 0u;
  }

  // ---- head pair-reduce via LDS (scratch region is free now) ----
  float* db = (float*)(lds + LDS_XF);   // [wave 16][ln 16][t 4]
  __syncthreads();                      // all plane reads (incl rescues) done
  if (g == 0) {
    #pragma unroll
    for (int t = 0; t < 4; ++t) db[(ot * 16 + ln) * 4 + t] = dsum[t];
  }
  __syncthreads();
  float at[4];
  {
    float tot[4];
    #pragma unroll
    for (int t = 0; t < 4; ++t)
      tot[t] = dsum[t] + db[((ot ^ 1) * 16 + ln) * 4 + t];   // exact ints
    float mgd = 1e30f;
    lif4m(tot[0], tot[1], tot[2], tot[3], 0.5f, at, mgd);    // exact dyadics
  }

  // ---- x_one = attn & k_s (binary bf16) -> plane 0 ----
  {
    const int chunk = ot * 2 + (g >> 1);
    const int j0 = (g & 1) * 4;
    #pragma unroll
    for (int t = 0; t < 4; ++t) {
      unsigned long long wbits = 0ull;
      #pragma unroll
      for (int r = 0; r < 4; ++r)
        if (((kb >> (r * 4 + t)) & 1u) && at[t] != 0.f)
          wbits |= 0x3F80ull << (r * 16);
      *(unsigned long long*)(lds + LDS_X + chunk * XCH +
                             (t * 16 + ln) * 16 + j0 * 2) = wbits;
    }
  }
  __syncthreads();   // x_one visible

  // ================= proj GEMM =================
  f32x4 ap[4];
  #pragma unroll
  for (int nt = 0; nt < 4; ++nt) ap[nt] = (f32x4)0.f;
  #pragma unroll 1
  for (int kk = 0; kk < 8; ++kk) {
    short8 fp_[3];
    #pragma unroll
    for (int p = 0; p < 3; ++p)
      fp_[p] = *(const short8*)(wp + (size_t)p * 131072 + (size_t)ot * 8192 +
                                kk * 1024 + lane * 16);
    #pragma unroll
    for (int nt = 0; nt < 4; ++nt) {
      const short8 b0 = *(const short8*)(lds + LDS_X +
                                         (kk * 4 + g) * XCH + (nt * 16 + ln) * 16);
      ap[nt] = MFMA(fp_[2], b0, ap[nt], 0, 0, 0);
      ap[nt] = MFMA(fp_[1], b0, ap[nt], 0, 0, 0);
      ap[nt] = MFMA(fp_[0], b0, ap[nt], 0, 0, 0);
    }
  }

  // ---- proj epilogue: bias + BN + LIF (+rescue) + store ----
  #pragma unroll
  for (int r = 0; r < 4; ++r) {
    const int o = ot * 16 + g * 4 + r;
    const float inv = p_gamma[o] / sqrtf(p_var[o] + EPSF);
    const float mn = p_mean[o], bt = p_beta[o], pb = proj_b[o];
    float pv[4];
    #pragma unroll
    for (int t = 0; t < 4; ++t) pv[t] = ((ap[t][r] + pb) - mn) * inv + bt;
    float sp[4], mg = 1e30f;
    lif4m(pv[0], pv[1], pv[2], pv[3], 1.0f, sp, mg);
    if (__builtin_expect(mg < EPS_R, 0)) {
      float px[4];
      rescue1(proj_w + (size_t)o * CC, lds, ln, px);
      #pragma unroll
      for (int t = 0; t < 4; ++t) px[t] = ((px[t] + pb) - mn) * inv + bt;
      float m2 = 1e30f;
      lif4m(px[0], px[1], px[2], px[3], 1.0f, sp, m2);
    }
    #pragma unroll
    for (int t = 0; t < 4; ++t)
      out[((size_t)(t * BB + b) * CC + o) * NN + n0 + ln] = sp[t];
  }
}

extern "C" void kernel_launch(void* const* d_in, const int* in_sizes, int n_in,
                              void* d_out, int out_size, void* d_ws, size_t ws_size,
                              hipStream_t stream) {
  const float* x       = (const float*)d_in[0];
  const float* q_w     = (const float*)d_in[1];
  const float* q_gamma = (const float*)d_in[2];
  const float* q_beta  = (const float*)d_in[3];
  const float* q_mean  = (const float*)d_in[4];
  const float* q_var   = (const float*)d_in[5];
  const float* k_w     = (const float*)d_in[6];
  const float* k_gamma = (const float*)d_in[7];
  const float* k_beta  = (const float*)d_in[8];
  const float* k_mean  = (const float*)d_in[9];
  const float* k_var   = (const float*)d_in[10];
  const float* proj_w  = (const float*)d_in[11];
  const float* proj_b  = (const float*)d_in[12];
  const float* p_gamma = (const float*)d_in[13];
  const float* p_beta  = (const float*)d_in[14];
  const float* p_mean  = (const float*)d_in[15];
  const float* p_var   = (const float*)d_in[16];
  float* out = (float*)d_out;
  uint16_t* wsp = (uint16_t*)d_ws;   // 1.125 MB split-weight fragment planes

  wsplit2<<<96, 256, 0, stream>>>(q_w, k_w, proj_w, wsp);
  pushpull_mfma4<<<BB * (NN / NT), 1024, 0, stream>>>(
      x, q_w, q_gamma, q_beta, q_mean, q_var,
      k_w, k_gamma, k_beta, k_mean, k_var,
      proj_w, proj_b, p_gamma, p_beta, p_mean, p_var, wsp, out);
}

// Round 12
// 145.027 us; speedup vs baseline: 17.2968x; 1.0715x over previous
//
#include <hip/hip_runtime.h>
#include <math.h>
#include <stdint.h>

// Problem constants
#define TT 4
#define BB 16
#define CC 256
#define NN 1024
#define NT 16        // spatial positions per block
#define EPSF 1e-5f
#define EPS_R 1e-5f  // rescue margin; 6-product GEMM error ~1e-6 (10x safety)

typedef __attribute__((ext_vector_type(8))) short short8;  // 8 bf16 (4 VGPR)
typedef __attribute__((ext_vector_type(4))) float f32x4;
#define MFMA __builtin_amdgcn_mfma_f32_16x16x32_bf16

// LDS geometry: 3 X planes + fp32 staging scratch = 134656 B (1 block/CU)
#define XCH 1040          // X-plane chunk stride (bytes): 1024 + 16 bank-shift
#define XPL 33280         // X plane = 32 chunks * 1040
#define LDS_X 0
#define LDS_XF 99840      // fp32 x scratch (128c * 68dw * 4B) / dsum exchange
#define LDS_TOT 134656

// bf16 split helpers (RNE). v == hi + mid + lo EXACTLY (3x8 >= 24 mantissa bits).
__device__ __forceinline__ uint32_t f2bf(float x) {
  const uint32_t u = __float_as_uint(x);
  return (u + 0x7FFFu + ((u >> 16) & 1u)) >> 16;
}
__device__ __forceinline__ float bf2f(uint32_t b) { return __uint_as_float(b << 16); }

// ---------------- weight pre-split kernel (identical to R10/R11) ------------
// ws bytes: mat*393216 + p*131072 + ot*8192 + kk*1024 + lane*16.
// Lane l: w_plane[o = ot*16 + (l&15)][k = kk*32 + (l>>4)*8 .. +8]
__global__ __launch_bounds__(256)
void wsplit2(const float* __restrict__ qw, const float* __restrict__ kw,
             const float* __restrict__ pw, uint16_t* __restrict__ ws) {
  const int gid = blockIdx.x * 256 + threadIdx.x;   // 24576 threads
  const int mat = gid >> 13;
  const int ot  = (gid >> 9) & 15;
  const int kk  = (gid >> 6) & 7;
  const int l   = gid & 63;
  const float* w = (mat == 0 ? qw : (mat == 1 ? kw : pw));
  const int o  = ot * 16 + (l & 15);
  const int k0 = kk * 32 + (l >> 4) * 8;
  uint16_t ph[8], pm[8], pl[8];
  #pragma unroll
  for (int j = 0; j < 8; ++j) {
    const float v = w[(size_t)o * CC + k0 + j];
    const uint32_t bh = f2bf(v);
    const float r1 = v - bf2f(bh);       // exact
    const uint32_t bm = f2bf(r1);
    const float r2 = r1 - bf2f(bm);      // exact
    ph[j] = (uint16_t)bh; pm[j] = (uint16_t)bm; pl[j] = (uint16_t)f2bf(r2);
  }
  const size_t base = ((size_t)mat * 3 * 65536) + ((size_t)ot * 4096) +
                      kk * 512 + l * 8;            // uint16 units
  *(uint4*)(ws + base)          = *(const uint4*)ph;
  *(uint4*)(ws + base + 65536)  = *(const uint4*)pm;   // plane stride 128KB
  *(uint4*)(ws + base + 131072) = *(const uint4*)pl;
}

// LIF (tau=2, hard reset) with decision-margin tracking.
__device__ __forceinline__ void lif4m(float q0, float q1, float q2, float q3,
                                      float th, float s[4], float& mg) {
  const float qq[4] = {q0, q1, q2, q3};
  float v = 0.f;
  #pragma unroll
  for (int t = 0; t < 4; ++t) {
    const float h = v + (qq[t] - v) * 0.5f;
    const float d = h - th;
    mg = fminf(mg, fabsf(d));
    const bool f = d >= 0.f;
    s[t] = f ? 1.f : 0.f;
    v = f ? 0.f : h;
  }
}

// Exact-chain rescue (q/k): x reconstructed exactly from the 3 LDS planes;
// strict ascending-c fmaf chain per t — bit-identical to the validated chain.
__device__ __forceinline__ void rescue3(const float* __restrict__ wrow,
                                        const char* lds, int ln, float sv[4]) {
  #pragma unroll
  for (int t = 0; t < 4; ++t) sv[t] = 0.f;
  #pragma unroll 1
  for (int c8 = 0; c8 < 32; ++c8) {
    const float4 wa = *(const float4*)(wrow + c8 * 8);
    const float4 wb = *(const float4*)(wrow + c8 * 8 + 4);
    const float wl_[8] = {wa.x, wa.y, wa.z, wa.w, wb.x, wb.y, wb.z, wb.w};
    #pragma unroll
    for (int t = 0; t < 4; ++t) {
      const int off = c8 * XCH + (t * 16 + ln) * 16;
      const short8 h = *(const short8*)(lds + LDS_X + 0 * XPL + off);
      const short8 m = *(const short8*)(lds + LDS_X + 1 * XPL + off);
      const short8 l = *(const short8*)(lds + LDS_X + 2 * XPL + off);
      float s = sv[t];
      #pragma unroll
      for (int j = 0; j < 8; ++j) {
        const float xv = (bf2f((uint16_t)h[j]) + bf2f((uint16_t)m[j])) +
                         bf2f((uint16_t)l[j]);
        s = fmaf(wl_[j], xv, s);
      }
      sv[t] = s;
    }
  }
}

// Exact-chain rescue (proj): x_one is binary, exact in plane 0.
__device__ __forceinline__ void rescue1(const float* __restrict__ wrow,
                                        const char* lds, int ln, float sv[4]) {
  #pragma unroll
  for (int t = 0; t < 4; ++t) sv[t] = 0.f;
  #pragma unroll 1
  for (int c8 = 0; c8 < 32; ++c8) {
    const float4 wa = *(const float4*)(wrow + c8 * 8);
    const float4 wb = *(const float4*)(wrow + c8 * 8 + 4);
    const float wl_[8] = {wa.x, wa.y, wa.z, wa.w, wb.x, wb.y, wb.z, wb.w};
    #pragma unroll
    for (int t = 0; t < 4; ++t) {
      const int off = c8 * XCH + (t * 16 + ln) * 16;
      const short8 h = *(const short8*)(lds + LDS_X + off);
      float s = sv[t];
      #pragma unroll
      for (int j = 0; j < 8; ++j)
        s = fmaf(wl_[j], bf2f((uint16_t)h[j]), s);
      sv[t] = s;
    }
  }
}

// 1024 thr = 16 waves (4/SIMD); wave = one 16-channel o-tile (ot).
// acc[nt][r]: o = ot*16 + g*4 + r, t = nt, n = ln -> LIF shuffle-free.
// Head h = waves {2h, 2h+1}; dsum pair-reduce via LDS exchange.
// R12: depth-1 named-buffer weight prefetch (A/B) + setprio around MFMA.
__global__ __launch_bounds__(1024, 4)
void pushpull_mfma5(const float* __restrict__ x,
                    const float* __restrict__ q_w, const float* __restrict__ q_gamma,
                    const float* __restrict__ q_beta, const float* __restrict__ q_mean,
                    const float* __restrict__ q_var,
                    const float* __restrict__ k_w, const float* __restrict__ k_gamma,
                    const float* __restrict__ k_beta, const float* __restrict__ k_mean,
                    const float* __restrict__ k_var,
                    const float* __restrict__ proj_w, const float* __restrict__ proj_b,
                    const float* __restrict__ p_gamma, const float* __restrict__ p_beta,
                    const float* __restrict__ p_mean, const float* __restrict__ p_var,
                    const uint16_t* __restrict__ ws, float* __restrict__ out) {
  __shared__ __align__(16) char lds[LDS_TOT];

  const int tid  = threadIdx.x;
  const int bid  = (int)blockIdx.x;
  const int lid  = ((bid & 7) << 7) | (bid >> 3);   // bijective XCD swizzle
  const int b    = lid >> 6;
  const int n0   = (lid & 63) * NT;
  const int lane = tid & 63;
  const int ln   = tid & 15;
  const int g    = (tid >> 4) & 3;
  const int ot   = tid >> 6;           // wave index = o-tile (16 channels)

  // ---- stage fp32 x + split-convert to 3 bf16 planes (2 half-passes) ----
  float* xf = (float*)(lds + LDS_XF);
  #pragma unroll 1
  for (int hb = 0; hb < 2; ++hb) {
    #pragma unroll
    for (int it = 0; it < 2; ++it) {
      const int idx = it * 1024 + tid;
      const int n4 = (idx & 3) * 4, t = (idx >> 2) & 3, cl = idx >> 4;
      const float4 v = *(const float4*)(
          x + ((size_t)(t * BB + b) * CC + hb * 128 + cl) * NN + n0 + n4);
      *(float4*)(xf + cl * 68 + t * 16 + n4) = v;
    }
    __syncthreads();
    {
      const int chL = tid >> 6, col = tid & 63;   // 16 chunks x 64 cols
      uint16_t ph[8], pm[8], pl[8];
      #pragma unroll
      for (int j = 0; j < 8; ++j) {
        const float v = xf[(chL * 8 + j) * 68 + col];
        const uint32_t bh = f2bf(v);
        const float r1 = v - bf2f(bh);
        const uint32_t bm = f2bf(r1);
        const float r2 = r1 - bf2f(bm);
        ph[j] = (uint16_t)bh; pm[j] = (uint16_t)bm; pl[j] = (uint16_t)f2bf(r2);
      }
      const int ca = (hb * 16 + chL) * XCH + col * 16;
      *(uint4*)(lds + LDS_X + 0 * XPL + ca) = *(const uint4*)ph;
      *(uint4*)(lds + LDS_X + 1 * XPL + ca) = *(const uint4*)pm;
      *(uint4*)(lds + LDS_X + 2 * XPL + ca) = *(const uint4*)pl;
    }
    __syncthreads();
  }

  const char* wq = (const char*)ws;                       // q planes
  const char* wk = (const char*)ws + 393216;              // k planes
  const char* wp = (const char*)ws + 786432;              // proj planes

  // ================= fused q + k GEMM (shared bf reads, A/B prefetch) ======
  f32x4 aq[4], ak[4];
  #pragma unroll
  for (int nt = 0; nt < 4; ++nt) { aq[nt] = (f32x4)0.f; ak[nt] = (f32x4)0.f; }

  short8 qA[3], kA[3], qB[3], kB[3];
#define LOADQK(DQ, DK, KK) do {                                               \
    _Pragma("unroll")                                                         \
    for (int p = 0; p < 3; ++p) {                                             \
      const size_t foff = (size_t)p * 131072 + (size_t)ot * 8192 +            \
                          (size_t)(KK) * 1024 + (size_t)lane * 16;            \
      DQ[p] = *(const short8*)(wq + foff);                                    \
      DK[p] = *(const short8*)(wk + foff);                                    \
    }                                                                         \
  } while (0)
  // product order per accumulator identical to R8-R11 (bit-exact)
#define STEPQK(FQ, FK, KK) do {                                               \
    __builtin_amdgcn_s_setprio(1);                                            \
    _Pragma("unroll")                                                         \
    for (int nt = 0; nt < 4; ++nt) {                                          \
      const int boff = ((KK) * 4 + g) * XCH + (nt * 16 + ln) * 16;            \
      const short8 b0 = *(const short8*)(lds + LDS_X + 0 * XPL + boff);       \
      const short8 b1 = *(const short8*)(lds + LDS_X + 1 * XPL + boff);       \
      const short8 b2 = *(const short8*)(lds + LDS_X + 2 * XPL + boff);       \
      aq[nt] = MFMA(FQ[2], b0, aq[nt], 0, 0, 0);                              \
      aq[nt] = MFMA(FQ[1], b1, aq[nt], 0, 0, 0);                              \
      aq[nt] = MFMA(FQ[0], b2, aq[nt], 0, 0, 0);                              \
      aq[nt] = MFMA(FQ[1], b0, aq[nt], 0, 0, 0);                              \
      aq[nt] = MFMA(FQ[0], b1, aq[nt], 0, 0, 0);                              \
      aq[nt] = MFMA(FQ[0], b0, aq[nt], 0, 0, 0);                              \
      ak[nt] = MFMA(FK[2], b0, ak[nt], 0, 0, 0);                              \
      ak[nt] = MFMA(FK[1], b1, ak[nt], 0, 0, 0);                              \
      ak[nt] = MFMA(FK[0], b2, ak[nt], 0, 0, 0);                              \
      ak[nt] = MFMA(FK[1], b0, ak[nt], 0, 0, 0);                              \
      ak[nt] = MFMA(FK[0], b1, ak[nt], 0, 0, 0);                              \
      ak[nt] = MFMA(FK[0], b0, ak[nt], 0, 0, 0);                              \
    }                                                                         \
    __builtin_amdgcn_s_setprio(0);                                            \
  } while (0)

  LOADQK(qA, kA, 0);
  #pragma unroll 1
  for (int kk2 = 0; kk2 < 4; ++kk2) {
    const int kk = kk2 * 2;
    LOADQK(qB, kB, kk + 1);
    STEPQK(qA, kA, kk);
    if (kk2 < 3) LOADQK(qA, kA, kk + 2);
    STEPQK(qB, kB, kk + 1);
  }

  // ---- q epilogue: BN + push/pull LIF (+rescue) -> dsum[t] ----
  float dsum[4] = {0.f, 0.f, 0.f, 0.f};
  #pragma unroll
  for (int r = 0; r < 4; ++r) {
    const int o = ot * 16 + g * 4 + r;
    const float inv = q_gamma[o] / sqrtf(q_var[o] + EPSF);
    const float mn = q_mean[o], bt = q_beta[o];
    float qv[4];
    #pragma unroll
    for (int t = 0; t < 4; ++t) qv[t] = (aq[t][r] - mn) * inv + bt;
    float se[4], si[4], mg = 1e30f;
    lif4m(qv[0], qv[1], qv[2], qv[3], 1.0f, se, mg);
    lif4m(-qv[0], -qv[1], -qv[2], -qv[3], 1.0f, si, mg);
    if (__builtin_expect(mg < EPS_R, 0)) {
      float qx[4];
      rescue3(q_w + (size_t)o * CC, lds, ln, qx);
      #pragma unroll
      for (int t = 0; t < 4; ++t) qx[t] = (qx[t] - mn) * inv + bt;
      float m2 = 1e30f;
      lif4m(qx[0], qx[1], qx[2], qx[3], 1.0f, se, m2);
      lif4m(-qx[0], -qx[1], -qx[2], -qx[3], 1.0f, si, m2);
    }
    #pragma unroll
    for (int t = 0; t < 4; ++t) dsum[t] += se[t] - si[t];   // exact ints
  }
  // reduce over the wave's 4 g-groups (16 channels), exact ints
  #pragma unroll
  for (int t = 0; t < 4; ++t) {
    float v = dsum[t];
    v += __shfl_xor(v, 16);
    v += __shfl_xor(v, 32);
    dsum[t] = v;
  }

  // ---- k epilogue: BN + LIF (+rescue) -> spike bits ----
  unsigned kb = 0u;   // bit r*4+t
  #pragma unroll
  for (int r = 0; r < 4; ++r) {
    const int o = ot * 16 + g * 4 + r;
    const float inv = k_gamma[o] / sqrtf(k_var[o] + EPSF);
    const float mn = k_mean[o], bt = k_beta[o];
    float kv[4];
    #pragma unroll
    for (int t = 0; t < 4; ++t) kv[t] = (ak[t][r] - mn) * inv + bt;
    float sk[4], mg = 1e30f;
    lif4m(kv[0], kv[1], kv[2], kv[3], 1.0f, sk, mg);
    if (__builtin_expect(mg < EPS_R, 0)) {
      float kx[4];
      rescue3(k_w + (size_t)o * CC, lds, ln, kx);
      #pragma unroll
      for (int t = 0; t < 4; ++t) kx[t] = (kx[t] - mn) * inv + bt;
      float m2 = 1e30f;
      lif4m(kx[0], kx[1], kx[2], kx[3], 1.0f, sk, m2);
    }
    #pragma unroll
    for (int t = 0; t < 4; ++t) kb |= (sk[t] != 0.f) ? (1u << (r * 4 + t)) : 0u;
  }

  // ---- head pair-reduce via LDS (scratch region is free now) ----
  float* db = (float*)(lds + LDS_XF);   // [wave 16][ln 16][t 4]
  __syncthreads();                      // all plane reads (incl rescues) done
  if (g == 0) {
    #pragma unroll
    for (int t = 0; t < 4; ++t) db[(ot * 16 + ln) * 4 + t] = dsum[t];
  }
  __syncthreads();
  float at[4];
  {
    float tot[4];
    #pragma unroll
    for (int t = 0; t < 4; ++t)
      tot[t] = dsum[t] + db[((ot ^ 1) * 16 + ln) * 4 + t];   // exact ints
    float mgd = 1e30f;
    lif4m(tot[0], tot[1], tot[2], tot[3], 0.5f, at, mgd);    // exact dyadics
  }

  // ---- x_one = attn & k_s (binary bf16) -> plane 0 ----
  {
    const int chunk = ot * 2 + (g >> 1);
    const int j0 = (g & 1) * 4;
    #pragma unroll
    for (int t = 0; t < 4; ++t) {
      unsigned long long wbits = 0ull;
      #pragma unroll
      for (int r = 0; r < 4; ++r)
        if (((kb >> (r * 4 + t)) & 1u) && at[t] != 0.f)
          wbits |= 0x3F80ull << (r * 16);
      *(unsigned long long*)(lds + LDS_X + chunk * XCH +
                             (t * 16 + ln) * 16 + j0 * 2) = wbits;
    }
  }
  __syncthreads();   // x_one visible

  // ================= proj GEMM (A/B prefetch) =================
  f32x4 ap[4];
  #pragma unroll
  for (int nt = 0; nt < 4; ++nt) ap[nt] = (f32x4)0.f;

  short8 pA[3], pB[3];
#define LOADP(DP, KK) do {                                                    \
    _Pragma("unroll")                                                         \
    for (int p = 0; p < 3; ++p)                                               \
      DP[p] = *(const short8*)(wp + (size_t)p * 131072 + (size_t)ot * 8192 +  \
                               (size_t)(KK) * 1024 + (size_t)lane * 16);      \
  } while (0)
#define STEPP(FP, KK) do {                                                    \
    __builtin_amdgcn_s_setprio(1);                                            \
    _Pragma("unroll")                                                         \
    for (int nt = 0; nt < 4; ++nt) {                                          \
      const short8 b0 = *(const short8*)(lds + LDS_X +                        \
                        ((KK) * 4 + g) * XCH + (nt * 16 + ln) * 16);          \
      ap[nt] = MFMA(FP[2], b0, ap[nt], 0, 0, 0);                              \
      ap[nt] = MFMA(FP[1], b0, ap[nt], 0, 0, 0);                              \
      ap[nt] = MFMA(FP[0], b0, ap[nt], 0, 0, 0);                              \
    }                                                                         \
    __builtin_amdgcn_s_setprio(0);                                            \
  } while (0)

  LOADP(pA, 0);
  #pragma unroll 1
  for (int kk2 = 0; kk2 < 4; ++kk2) {
    const int kk = kk2 * 2;
    LOADP(pB, kk + 1);
    STEPP(pA, kk);
    if (kk2 < 3) LOADP(pA, kk + 2);
    STEPP(pB, kk + 1);
  }

  // ---- proj epilogue: bias + BN + LIF (+rescue) + store ----
  #pragma unroll
  for (int r = 0; r < 4; ++r) {
    const int o = ot * 16 + g * 4 + r;
    const float inv = p_gamma[o] / sqrtf(p_var[o] + EPSF);
    const float mn = p_mean[o], bt = p_beta[o], pb = proj_b[o];
    float pv[4];
    #pragma unroll
    for (int t = 0; t < 4; ++t) pv[t] = ((ap[t][r] + pb) - mn) * inv + bt;
    float sp[4], mg = 1e30f;
    lif4m(pv[0], pv[1], pv[2], pv[3], 1.0f, sp, mg);
    if (__builtin_expect(mg < EPS_R, 0)) {
      float px[4];
      rescue1(proj_w + (size_t)o * CC, lds, ln, px);
      #pragma unroll
      for (int t = 0; t < 4; ++t) px[t] = ((px[t] + pb) - mn) * inv + bt;
      float m2 = 1e30f;
      lif4m(px[0], px[1], px[2], px[3], 1.0f, sp, m2);
    }
    #pragma unroll
    for (int t = 0; t < 4; ++t)
      out[((size_t)(t * BB + b) * CC + o) * NN + n0 + ln] = sp[t];
  }
}

extern "C" void kernel_launch(void* const* d_in, const int* in_sizes, int n_in,
                              void* d_out, int out_size, void* d_ws, size_t ws_size,
                              hipStream_t stream) {
  const float* x       = (const float*)d_in[0];
  const float* q_w     = (const float*)d_in[1];
  const float* q_gamma = (const float*)d_in[2];
  const float* q_beta  = (const float*)d_in[3];
  const float* q_mean  = (const float*)d_in[4];
  const float* q_var   = (const float*)d_in[5];
  const float* k_w     = (const float*)d_in[6];
  const float* k_gamma = (const float*)d_in[7];
  const float* k_beta  = (const float*)d_in[8];
  const float* k_mean  = (const float*)d_in[9];
  const float* k_var   = (const float*)d_in[10];
  const float* proj_w  = (const float*)d_in[11];
  const float* proj_b  = (const float*)d_in[12];
  const float* p_gamma = (const float*)d_in[13];
  const float* p_beta  = (const float*)d_in[14];
  const float* p_mean  = (const float*)d_in[15];
  const float* p_var   = (const float*)d_in[16];
  float* out = (float*)d_out;
  uint16_t* wsp = (uint16_t*)d_ws;   // 1.125 MB split-weight fragment planes

  wsplit2<<<96, 256, 0, stream>>>(q_w, k_w, proj_w, wsp);
  pushpull_mfma5<<<BB * (NN / NT), 1024, 0, stream>>>(
      x, q_w, q_gamma, q_beta, q_mean, q_var,
      k_w, k_gamma, k_beta, k_mean, k_var,
      proj_w, proj_b, p_gamma, p_beta, p_mean, p_var, wsp, out);
}

// Round 13
// 125.965 us; speedup vs baseline: 19.9143x; 1.1513x over previous
//
#include <hip/hip_runtime.h>
#include <math.h>
#include <stdint.h>

// Problem constants
#define TT 4
#define BB 16
#define CC 256
#define NN 1024
#define NT 16        // spatial positions per block
#define EPSF 1e-5f
// Rescue margin. 3-product q/k GEMM error sigma ~3e-6 (post-BN ~4.2e-6);
// 6e-5 = ~14 sigma — larger protection ratio than the validated 6-product
// config (1e-5 vs sigma ~1e-6 = 10 sigma, passed R8-R12). Decisions with
// margin < EPS_R are recomputed with the exact fp32 chain (bit-identical
// to reference), so final spikes are exact regardless of GEMM rounding.
#define EPS_R 6e-5f

typedef __attribute__((ext_vector_type(8))) short short8;  // 8 bf16 (4 VGPR)
typedef __attribute__((ext_vector_type(4))) float f32x4;
#define MFMA __builtin_amdgcn_mfma_f32_16x16x32_bf16

// LDS geometry: 3 X planes + fp32 staging scratch = 134656 B (1 block/CU)
#define XCH 1040          // X-plane chunk stride (bytes): 1024 + 16 bank-shift
#define XPL 33280         // X plane = 32 chunks * 1040
#define LDS_X 0
#define LDS_XF 99840      // fp32 x scratch (128c * 68dw * 4B) / dsum exchange
#define LDS_TOT 134656

// bf16 split helpers (RNE). v == hi + mid + lo EXACTLY (3x8 >= 24 mantissa bits).
__device__ __forceinline__ uint32_t f2bf(float x) {
  const uint32_t u = __float_as_uint(x);
  return (u + 0x7FFFu + ((u >> 16) & 1u)) >> 16;
}
__device__ __forceinline__ float bf2f(uint32_t b) { return __uint_as_float(b << 16); }

// ---------------- weight pre-split kernel (identical layout to R10-R12) -----
// ws bytes: mat*393216 + p*131072 + ot*8192 + kk*1024 + lane*16.
// Lane l: w_plane[o = ot*16 + (l&15)][k = kk*32 + (l>>4)*8 .. +8]
// (plane 2 = lo is kept for layout stability; GEMM no longer reads it.)
__global__ __launch_bounds__(256)
void wsplit2(const float* __restrict__ qw, const float* __restrict__ kw,
             const float* __restrict__ pw, uint16_t* __restrict__ ws) {
  const int gid = blockIdx.x * 256 + threadIdx.x;   // 24576 threads
  const int mat = gid >> 13;
  const int ot  = (gid >> 9) & 15;
  const int kk  = (gid >> 6) & 7;
  const int l   = gid & 63;
  const float* w = (mat == 0 ? qw : (mat == 1 ? kw : pw));
  const int o  = ot * 16 + (l & 15);
  const int k0 = kk * 32 + (l >> 4) * 8;
  uint16_t ph[8], pm[8], pl[8];
  #pragma unroll
  for (int j = 0; j < 8; ++j) {
    const float v = w[(size_t)o * CC + k0 + j];
    const uint32_t bh = f2bf(v);
    const float r1 = v - bf2f(bh);       // exact
    const uint32_t bm = f2bf(r1);
    const float r2 = r1 - bf2f(bm);      // exact
    ph[j] = (uint16_t)bh; pm[j] = (uint16_t)bm; pl[j] = (uint16_t)f2bf(r2);
  }
  const size_t base = ((size_t)mat * 3 * 65536) + ((size_t)ot * 4096) +
                      kk * 512 + l * 8;            // uint16 units
  *(uint4*)(ws + base)          = *(const uint4*)ph;
  *(uint4*)(ws + base + 65536)  = *(const uint4*)pm;   // plane stride 128KB
  *(uint4*)(ws + base + 131072) = *(const uint4*)pl;
}

// LIF (tau=2, hard reset) with decision-margin tracking.
__device__ __forceinline__ void lif4m(float q0, float q1, float q2, float q3,
                                      float th, float s[4], float& mg) {
  const float qq[4] = {q0, q1, q2, q3};
  float v = 0.f;
  #pragma unroll
  for (int t = 0; t < 4; ++t) {
    const float h = v + (qq[t] - v) * 0.5f;
    const float d = h - th;
    mg = fminf(mg, fabsf(d));
    const bool f = d >= 0.f;
    s[t] = f ? 1.f : 0.f;
    v = f ? 0.f : h;
  }
}

// Exact-chain rescue (q/k): x reconstructed exactly from the 3 LDS planes
// (hi+mid+lo is an exact fp32 split); strict ascending-c fmaf chain per t —
// bit-identical to the validated reference chain (R8-R12).
__device__ __forceinline__ void rescue3(const float* __restrict__ wrow,
                                        const char* lds, int ln, float sv[4]) {
  #pragma unroll
  for (int t = 0; t < 4; ++t) sv[t] = 0.f;
  #pragma unroll 1
  for (int c8 = 0; c8 < 32; ++c8) {
    const float4 wa = *(const float4*)(wrow + c8 * 8);
    const float4 wb = *(const float4*)(wrow + c8 * 8 + 4);
    const float wl_[8] = {wa.x, wa.y, wa.z, wa.w, wb.x, wb.y, wb.z, wb.w};
    #pragma unroll
    for (int t = 0; t < 4; ++t) {
      const int off = c8 * XCH + (t * 16 + ln) * 16;
      const short8 h = *(const short8*)(lds + LDS_X + 0 * XPL + off);
      const short8 m = *(const short8*)(lds + LDS_X + 1 * XPL + off);
      const short8 l = *(const short8*)(lds + LDS_X + 2 * XPL + off);
      float s = sv[t];
      #pragma unroll
      for (int j = 0; j < 8; ++j) {
        const float xv = (bf2f((uint16_t)h[j]) + bf2f((uint16_t)m[j])) +
                         bf2f((uint16_t)l[j]);
        s = fmaf(wl_[j], xv, s);
      }
      sv[t] = s;
    }
  }
}

// Exact-chain rescue (proj): x_one is binary, exact in plane 0.
__device__ __forceinline__ void rescue1(const float* __restrict__ wrow,
                                        const char* lds, int ln, float sv[4]) {
  #pragma unroll
  for (int t = 0; t < 4; ++t) sv[t] = 0.f;
  #pragma unroll 1
  for (int c8 = 0; c8 < 32; ++c8) {
    const float4 wa = *(const float4*)(wrow + c8 * 8);
    const float4 wb = *(const float4*)(wrow + c8 * 8 + 4);
    const float wl_[8] = {wa.x, wa.y, wa.z, wa.w, wb.x, wb.y, wb.z, wb.w};
    #pragma unroll
    for (int t = 0; t < 4; ++t) {
      const int off = c8 * XCH + (t * 16 + ln) * 16;
      const short8 h = *(const short8*)(lds + LDS_X + off);
      float s = sv[t];
      #pragma unroll
      for (int j = 0; j < 8; ++j)
        s = fmaf(wl_[j], bf2f((uint16_t)h[j]), s);
      sv[t] = s;
    }
  }
}

// 1024 thr = 16 waves (4/SIMD); wave = one 16-channel o-tile (ot).
// acc[nt][r]: o = ot*16 + g*4 + r, t = nt, n = ln -> LIF shuffle-free.
// R13: 3-product q/k GEMM {wh*xh, wh*xm, wm*xh}, 2-product proj {wh, wm};
// dropped terms (sigma ~3e-6) are covered by EPS_R=6e-5 + exact rescue.
// MFMA work drops 480 -> 320... -> 256+64 per wave (40% of dominant pipe).
__global__ __launch_bounds__(1024, 4)
void pushpull_mfma6(const float* __restrict__ x,
                    const float* __restrict__ q_w, const float* __restrict__ q_gamma,
                    const float* __restrict__ q_beta, const float* __restrict__ q_mean,
                    const float* __restrict__ q_var,
                    const float* __restrict__ k_w, const float* __restrict__ k_gamma,
                    const float* __restrict__ k_beta, const float* __restrict__ k_mean,
                    const float* __restrict__ k_var,
                    const float* __restrict__ proj_w, const float* __restrict__ proj_b,
                    const float* __restrict__ p_gamma, const float* __restrict__ p_beta,
                    const float* __restrict__ p_mean, const float* __restrict__ p_var,
                    const uint16_t* __restrict__ ws, float* __restrict__ out) {
  __shared__ __align__(16) char lds[LDS_TOT];

  const int tid  = threadIdx.x;
  const int bid  = (int)blockIdx.x;
  const int lid  = ((bid & 7) << 7) | (bid >> 3);   // bijective XCD swizzle
  const int b    = lid >> 6;
  const int n0   = (lid & 63) * NT;
  const int lane = tid & 63;
  const int ln   = tid & 15;
  const int g    = (tid >> 4) & 3;
  const int ot   = tid >> 6;           // wave index = o-tile (16 channels)

  // ---- stage fp32 x + split-convert to 3 bf16 planes (2 half-passes) ----
  // (lo plane is written for the exact rescue path only.)
  float* xf = (float*)(lds + LDS_XF);
  #pragma unroll 1
  for (int hb = 0; hb < 2; ++hb) {
    #pragma unroll
    for (int it = 0; it < 2; ++it) {
      const int idx = it * 1024 + tid;
      const int n4 = (idx & 3) * 4, t = (idx >> 2) & 3, cl = idx >> 4;
      const float4 v = *(const float4*)(
          x + ((size_t)(t * BB + b) * CC + hb * 128 + cl) * NN + n0 + n4);
      *(float4*)(xf + cl * 68 + t * 16 + n4) = v;
    }
    __syncthreads();
    {
      const int chL = tid >> 6, col = tid & 63;   // 16 chunks x 64 cols
      uint16_t ph[8], pm[8], pl[8];
      #pragma unroll
      for (int j = 0; j < 8; ++j) {
        const float v = xf[(chL * 8 + j) * 68 + col];
        const uint32_t bh = f2bf(v);
        const float r1 = v - bf2f(bh);
        const uint32_t bm = f2bf(r1);
        const float r2 = r1 - bf2f(bm);
        ph[j] = (uint16_t)bh; pm[j] = (uint16_t)bm; pl[j] = (uint16_t)f2bf(r2);
      }
      const int ca = (hb * 16 + chL) * XCH + col * 16;
      *(uint4*)(lds + LDS_X + 0 * XPL + ca) = *(const uint4*)ph;
      *(uint4*)(lds + LDS_X + 1 * XPL + ca) = *(const uint4*)pm;
      *(uint4*)(lds + LDS_X + 2 * XPL + ca) = *(const uint4*)pl;
    }
    __syncthreads();
  }

  const char* wq = (const char*)ws;                       // q planes
  const char* wk = (const char*)ws + 393216;              // k planes
  const char* wp = (const char*)ws + 786432;              // proj planes

  // ====== fused q + k GEMM: 3 products each, shared b reads, A/B prefetch ===
  f32x4 aq[4], ak[4];
  #pragma unroll
  for (int nt = 0; nt < 4; ++nt) { aq[nt] = (f32x4)0.f; ak[nt] = (f32x4)0.f; }

  short8 qA[2], kA[2], qB[2], kB[2];
#define LOADQK(DQ, DK, KK) do {                                               \
    _Pragma("unroll")                                                         \
    for (int p = 0; p < 2; ++p) {                                             \
      const size_t foff = (size_t)p * 131072 + (size_t)ot * 8192 +            \
                          (size_t)(KK) * 1024 + (size_t)lane * 16;            \
      DQ[p] = *(const short8*)(wq + foff);                                    \
      DK[p] = *(const short8*)(wk + foff);                                    \
    }                                                                         \
  } while (0)
  // products small->large: wm*xh, wh*xm, wh*xh (dropped terms rescued)
#define STEPQK(FQ, FK, KK) do {                                               \
    __builtin_amdgcn_s_setprio(1);                                            \
    _Pragma("unroll")                                                         \
    for (int nt = 0; nt < 4; ++nt) {                                          \
      const int boff = ((KK) * 4 + g) * XCH + (nt * 16 + ln) * 16;            \
      const short8 b0 = *(const short8*)(lds + LDS_X + 0 * XPL + boff);       \
      const short8 b1 = *(const short8*)(lds + LDS_X + 1 * XPL + boff);       \
      aq[nt] = MFMA(FQ[1], b0, aq[nt], 0, 0, 0);                              \
      aq[nt] = MFMA(FQ[0], b1, aq[nt], 0, 0, 0);                              \
      aq[nt] = MFMA(FQ[0], b0, aq[nt], 0, 0, 0);                              \
      ak[nt] = MFMA(FK[1], b0, ak[nt], 0, 0, 0);                              \
      ak[nt] = MFMA(FK[0], b1, ak[nt], 0, 0, 0);                              \
      ak[nt] = MFMA(FK[0], b0, ak[nt], 0, 0, 0);                              \
    }                                                                         \
    __builtin_amdgcn_s_setprio(0);                                            \
  } while (0)

  LOADQK(qA, kA, 0);
  #pragma unroll 1
  for (int kk2 = 0; kk2 < 4; ++kk2) {
    const int kk = kk2 * 2;
    LOADQK(qB, kB, kk + 1);
    STEPQK(qA, kA, kk);
    if (kk2 < 3) LOADQK(qA, kA, kk + 2);
    STEPQK(qB, kB, kk + 1);
  }

  // ---- q epilogue: BN + push/pull LIF (+rescue) -> dsum[t] ----
  float dsum[4] = {0.f, 0.f, 0.f, 0.f};
  #pragma unroll
  for (int r = 0; r < 4; ++r) {
    const int o = ot * 16 + g * 4 + r;
    const float inv = q_gamma[o] / sqrtf(q_var[o] + EPSF);
    const float mn = q_mean[o], bt = q_beta[o];
    float qv[4];
    #pragma unroll
    for (int t = 0; t < 4; ++t) qv[t] = (aq[t][r] - mn) * inv + bt;
    float se[4], si[4], mg = 1e30f;
    lif4m(qv[0], qv[1], qv[2], qv[3], 1.0f, se, mg);
    lif4m(-qv[0], -qv[1], -qv[2], -qv[3], 1.0f, si, mg);
    if (__builtin_expect(mg < EPS_R, 0)) {
      float qx[4];
      rescue3(q_w + (size_t)o * CC, lds, ln, qx);
      #pragma unroll
      for (int t = 0; t < 4; ++t) qx[t] = (qx[t] - mn) * inv + bt;
      float m2 = 1e30f;
      lif4m(qx[0], qx[1], qx[2], qx[3], 1.0f, se, m2);
      lif4m(-qx[0], -qx[1], -qx[2], -qx[3], 1.0f, si, m2);
    }
    #pragma unroll
    for (int t = 0; t < 4; ++t) dsum[t] += se[t] - si[t];   // exact ints
  }
  // reduce over the wave's 4 g-groups (16 channels), exact ints
  #pragma unroll
  for (int t = 0; t < 4; ++t) {
    float v = dsum[t];
    v += __shfl_xor(v, 16);
    v += __shfl_xor(v, 32);
    dsum[t] = v;
  }

  // ---- k epilogue: BN + LIF (+rescue) -> spike bits ----
  unsigned kb = 0u;   // bit r*4+t
  #pragma unroll
  for (int r = 0; r < 4; ++r) {
    const int o = ot * 16 + g * 4 + r;
    const float inv = k_gamma[o] / sqrtf(k_var[o] + EPSF);
    const float mn = k_mean[o], bt = k_beta[o];
    float kv[4];
    #pragma unroll
    for (int t = 0; t < 4; ++t) kv[t] = (ak[t][r] - mn) * inv + bt;
    float sk[4], mg = 1e30f;
    lif4m(kv[0], kv[1], kv[2], kv[3], 1.0f, sk, mg);
    if (__builtin_expect(mg < EPS_R, 0)) {
      float kx[4];
      rescue3(k_w + (size_t)o * CC, lds, ln, kx);
      #pragma unroll
      for (int t = 0; t < 4; ++t) kx[t] = (kx[t] - mn) * inv + bt;
      float m2 = 1e30f;
      lif4m(kx[0], kx[1], kx[2], kx[3], 1.0f, sk, m2);
    }
    #pragma unroll
    for (int t = 0; t < 4; ++t) kb |= (sk[t] != 0.f) ? (1u << (r * 4 + t)) : 0u;
  }

  // ---- head pair-reduce via LDS (scratch region is free now) ----
  float* db = (float*)(lds + LDS_XF);   // [wave 16][ln 16][t 4]
  __syncthreads();                      // all plane reads (incl rescues) done
  if (g == 0) {
    #pragma unroll
    for (int t = 0; t < 4; ++t) db[(ot * 16 + ln) * 4 + t] = dsum[t];
  }
  __syncthreads();
  float at[4];
  {
    float tot[4];
    #pragma unroll
    for (int t = 0; t < 4; ++t)
      tot[t] = dsum[t] + db[((ot ^ 1) * 16 + ln) * 4 + t];   // exact ints
    float mgd = 1e30f;
    lif4m(tot[0], tot[1], tot[2], tot[3], 0.5f, at, mgd);    // exact dyadics
  }

  // ---- x_one = attn & k_s (binary bf16) -> plane 0 ----
  {
    const int chunk = ot * 2 + (g >> 1);
    const int j0 = (g & 1) * 4;
    #pragma unroll
    for (int t = 0; t < 4; ++t) {
      unsigned long long wbits = 0ull;
      #pragma unroll
      for (int r = 0; r < 4; ++r)
        if (((kb >> (r * 4 + t)) & 1u) && at[t] != 0.f)
          wbits |= 0x3F80ull << (r * 16);
      *(unsigned long long*)(lds + LDS_X + chunk * XCH +
                             (t * 16 + ln) * 16 + j0 * 2) = wbits;
    }
  }
  __syncthreads();   // x_one visible

  // ================= proj GEMM: 2 products (x_one exact in plane 0) ========
  f32x4 ap[4];
  #pragma unroll
  for (int nt = 0; nt < 4; ++nt) ap[nt] = (f32x4)0.f;

  short8 pA[2], pB[2];
#define LOADP(DP, KK) do {                                                    \
    _Pragma("unroll")                                                         \
    for (int p = 0; p < 2; ++p)                                               \
      DP[p] = *(const short8*)(wp + (size_t)p * 131072 + (size_t)ot * 8192 +  \
                               (size_t)(KK) * 1024 + (size_t)lane * 16);      \
  } while (0)
#define STEPP(FP, KK) do {                                                    \
    __builtin_amdgcn_s_setprio(1);                                            \
    _Pragma("unroll")                                                         \
    for (int nt = 0; nt < 4; ++nt) {                                          \
      const short8 b0 = *(const short8*)(lds + LDS_X +                        \
                        ((KK) * 4 + g) * XCH + (nt * 16 + ln) * 16);          \
      ap[nt] = MFMA(FP[1], b0, ap[nt], 0, 0, 0);                              \
      ap[nt] = MFMA(FP[0], b0, ap[nt], 0, 0, 0);                              \
    }                                                                         \
    __builtin_amdgcn_s_setprio(0);                                            \
  } while (0)

  LOADP(pA, 0);
  #pragma unroll 1
  for (int kk2 = 0; kk2 < 4; ++kk2) {
    const int kk = kk2 * 2;
    LOADP(pB, kk + 1);
    STEPP(pA, kk);
    if (kk2 < 3) LOADP(pA, kk + 2);
    STEPP(pB, kk + 1);
  }

  // ---- proj epilogue: bias + BN + LIF (+rescue) + store ----
  #pragma unroll
  for (int r = 0; r < 4; ++r) {
    const int o = ot * 16 + g * 4 + r;
    const float inv = p_gamma[o] / sqrtf(p_var[o] + EPSF);
    const float mn = p_mean[o], bt = p_beta[o], pb = proj_b[o];
    float pv[4];
    #pragma unroll
    for (int t = 0; t < 4; ++t) pv[t] = ((ap[t][r] + pb) - mn) * inv + bt;
    float sp[4], mg = 1e30f;
    lif4m(pv[0], pv[1], pv[2], pv[3], 1.0f, sp, mg);
    if (__builtin_expect(mg < EPS_R, 0)) {
      float px[4];
      rescue1(proj_w + (size_t)o * CC, lds, ln, px);
      #pragma unroll
      for (int t = 0; t < 4; ++t) px[t] = ((px[t] + pb) - mn) * inv + bt;
      float m2 = 1e30f;
      lif4m(px[0], px[1], px[2], px[3], 1.0f, sp, m2);
    }
    #pragma unroll
    for (int t = 0; t < 4; ++t)
      out[((size_t)(t * BB + b) * CC + o) * NN + n0 + ln] = sp[t];
  }
}

extern "C" void kernel_launch(void* const* d_in, const int* in_sizes, int n_in,
                              void* d_out, int out_size, void* d_ws, size_t ws_size,
                              hipStream_t stream) {
  const float* x       = (const float*)d_in[0];
  const float* q_w     = (const float*)d_in[1];
  const float* q_gamma = (const float*)d_in[2];
  const float* q_beta  = (const float*)d_in[3];
  const float* q_mean  = (const float*)d_in[4];
  const float* q_var   = (const float*)d_in[5];
  const float* k_w     = (const float*)d_in[6];
  const float* k_gamma = (const float*)d_in[7];
  const float* k_beta  = (const float*)d_in[8];
  const float* k_mean  = (const float*)d_in[9];
  const float* k_var   = (const float*)d_in[10];
  const float* proj_w  = (const float*)d_in[11];
  const float* proj_b  = (const float*)d_in[12];
  const float* p_gamma = (const float*)d_in[13];
  const float* p_beta  = (const float*)d_in[14];
  const float* p_mean  = (const float*)d_in[15];
  const float* p_var   = (const float*)d_in[16];
  float* out = (float*)d_out;
  uint16_t* wsp = (uint16_t*)d_ws;   // 1.125 MB split-weight fragment planes

  wsplit2<<<96, 256, 0, stream>>>(q_w, k_w, proj_w, wsp);
  pushpull_mfma6<<<BB * (NN / NT), 1024, 0, stream>>>(
      x, q_w, q_gamma, q_beta, q_mean, q_var,
      k_w, k_gamma, k_beta, k_mean, k_var,
      proj_w, proj_b, p_gamma, p_beta, p_mean, p_var, wsp, out);
}